// Round 15
// baseline (854.746 us; speedup 1.0000x reference)
//
#include <hip/hip_runtime.h>
#include <hip/hip_bf16.h>
#include <math.h>
#include <float.h>

#define BB   4
#define N1   1024
#define N2   4096
#define CIN  512
#define CC   256
#define DM   256
#define KNNK 16
#define PPB  4    // points per attention block

typedef __attribute__((ext_vector_type(8))) short bf16x8;
typedef __attribute__((ext_vector_type(4))) float f32x4;

__device__ __forceinline__ float bf16r(float x) {
    return __bfloat162float(__float2bfloat16(x));
}
__device__ __forceinline__ unsigned short f2bu(float x) {
    __hip_bfloat16 h = __float2bfloat16(x);
    return *reinterpret_cast<unsigned short*>(&h);
}
__device__ __forceinline__ float bu2f(unsigned short u) {
    __hip_bfloat16 h = *reinterpret_cast<__hip_bfloat16*>(&u);
    return __bfloat162float(h);
}

// ---------------------------------------------------------------------------
// All 10 weight swizzles in one launch. B-frag layout identical to before:
// B[((kb*16+tile)*64+l)*8 + i] = bf16(W[kb*32+(l>>4)*8+i][tile*16+(l&15)])
// ---------------------------------------------------------------------------
struct SwzArgs {
    const float* W[10];
    unsigned short* B[10];
    int K[10];
};
__global__ __launch_bounds__(256) void swizzle_all(SwzArgs a)
{
    int m = blockIdx.y;
    int idx = blockIdx.x * 256 + threadIdx.x;
    int total = (a.K[m] >> 5) << 10;
    if (idx >= total) return;
    const float* W = a.W[m];
    unsigned short* B = a.B[m];
    int l = idx & 63;
    int tile = (idx >> 6) & 15;
    int kb = idx >> 10;
    int col = tile * 16 + (l & 15);
    int k0 = kb * 32 + ((l >> 4) << 3);
#pragma unroll
    for (int i = 0; i < 8; ++i)
        B[(size_t)idx * 8 + i] = f2bu(W[(size_t)(k0 + i) * 256 + col]);
}

// ---------------------------------------------------------------------------
// MFMA GEMM, N-split (unchanged from round 14 — bit-identical)
// ---------------------------------------------------------------------------
template<int KD, int NT, bool RELU, bool BN_, bool RESID>
__global__ __launch_bounds__(256) void gemm_mfma(
    const float* __restrict__ X, const unsigned short* __restrict__ Bw,
    const float* __restrict__ bias, const float* __restrict__ resid,
    float scale, float* __restrict__ Y)
{
    const int NSPLIT = 16 / NT;
    const int c = threadIdx.x;
    const int l = c & 63, wv_ = c >> 6;
    const int lr = l & 15, lg = l >> 4;
    const int row0 = (blockIdx.x / NSPLIT) * 64;
    const int tb = (blockIdx.x % NSPLIT) * NT;
    __shared__ __align__(16) unsigned short As[64][72];

    f32x4 acc[NT];
#pragma unroll
    for (int t = 0; t < NT; ++t) acc[t] = (f32x4){0.f, 0.f, 0.f, 0.f};

    const int rs = c >> 2, c0 = (c & 3) * 16;
    for (int ks = 0; ks < KD / 64; ++ks) {
        const float* src = X + (size_t)(row0 + rs) * KD + ks * 64 + c0;
#pragma unroll
        for (int i = 0; i < 16; i += 4) {
            float4 v = *(const float4*)(src + i);
            As[rs][c0 + i + 0] = f2bu(v.x);
            As[rs][c0 + i + 1] = f2bu(v.y);
            As[rs][c0 + i + 2] = f2bu(v.z);
            As[rs][c0 + i + 3] = f2bu(v.w);
        }
        __syncthreads();
#pragma unroll
        for (int kbl = 0; kbl < 2; ++kbl) {
            int kb = ks * 2 + kbl;
            bf16x8 af = *(const bf16x8*)&As[wv_ * 16 + lr][kbl * 32 + lg * 8];
#pragma unroll
            for (int t = 0; t < NT; ++t) {
                bf16x8 bf = *(const bf16x8*)&Bw[((size_t)(kb * 16 + tb + t) * 64 + l) * 8];
                acc[t] = __builtin_amdgcn_mfma_f32_16x16x32_bf16(af, bf, acc[t], 0, 0, 0);
            }
        }
        __syncthreads();
    }
#pragma unroll
    for (int t = 0; t < NT; ++t) {
        int col = (tb + t) * 16 + lr;
        float bb = bias ? bias[col] : 0.f;
#pragma unroll
        for (int r = 0; r < 4; ++r) {
            size_t row = row0 + wv_ * 16 + lg * 4 + r;
            float v = bf16r(acc[t][r]);
            v = bf16r(v + bb);
            if (BN_) v = bf16r(v * scale);
            if (RELU) v = fmaxf(v, 0.f);
            if (RESID) v = bf16r(v + resid[row * 256 + col]);
            Y[row * 256 + col] = v;
        }
    }
}

// ---------------------------------------------------------------------------
// Fused q/k/v GEMM (unchanged from round 14 — bit-identical)
// ---------------------------------------------------------------------------
__global__ __launch_bounds__(256) void qkv_mfma(
    const float* __restrict__ X,
    const unsigned short* __restrict__ Bq,
    const unsigned short* __restrict__ Bk,
    const unsigned short* __restrict__ Bv,
    float* __restrict__ Yq, float* __restrict__ Yk, float* __restrict__ Yv)
{
    const int NT = 8;
    const int c = threadIdx.x;
    const int l = c & 63, wv_ = c >> 6;
    const int lr = l & 15, lg = l >> 4;
    const int row0 = (blockIdx.x >> 1) * 64;
    const int tb = (blockIdx.x & 1) * NT;
    __shared__ __align__(16) unsigned short As[64][72];

    f32x4 aq[NT], ak[NT], av_[NT];
#pragma unroll
    for (int t = 0; t < NT; ++t) {
        aq[t] = (f32x4){0.f, 0.f, 0.f, 0.f};
        ak[t] = aq[t]; av_[t] = aq[t];
    }

    const int rs = c >> 2, c0 = (c & 3) * 16;
    for (int ks = 0; ks < CC / 64; ++ks) {
        const float* src = X + (size_t)(row0 + rs) * CC + ks * 64 + c0;
#pragma unroll
        for (int i = 0; i < 16; i += 4) {
            float4 v = *(const float4*)(src + i);
            As[rs][c0 + i + 0] = f2bu(v.x);
            As[rs][c0 + i + 1] = f2bu(v.y);
            As[rs][c0 + i + 2] = f2bu(v.z);
            As[rs][c0 + i + 3] = f2bu(v.w);
        }
        __syncthreads();
#pragma unroll
        for (int kbl = 0; kbl < 2; ++kbl) {
            int kb = ks * 2 + kbl;
            bf16x8 af = *(const bf16x8*)&As[wv_ * 16 + lr][kbl * 32 + lg * 8];
#pragma unroll
            for (int t = 0; t < NT; ++t) {
                size_t fo = ((size_t)(kb * 16 + tb + t) * 64 + l) * 8;
                bf16x8 bq = *(const bf16x8*)&Bq[fo];
                bf16x8 bk = *(const bf16x8*)&Bk[fo];
                bf16x8 bv = *(const bf16x8*)&Bv[fo];
                aq[t]  = __builtin_amdgcn_mfma_f32_16x16x32_bf16(af, bq, aq[t], 0, 0, 0);
                ak[t]  = __builtin_amdgcn_mfma_f32_16x16x32_bf16(af, bk, ak[t], 0, 0, 0);
                av_[t] = __builtin_amdgcn_mfma_f32_16x16x32_bf16(af, bv, av_[t], 0, 0, 0);
            }
        }
        __syncthreads();
    }
#pragma unroll
    for (int t = 0; t < NT; ++t) {
        int col = (tb + t) * 16 + lr;
#pragma unroll
        for (int r = 0; r < 4; ++r) {
            size_t row = row0 + wv_ * 16 + lg * 4 + r;
            Yq[row * 256 + col] = bf16r(bf16r(aq[t][r]));
            Yk[row * 256 + col] = bf16r(bf16r(ak[t][r]));
            Yv[row * 256 + col] = bf16r(bf16r(av_[t][r]));
        }
    }
}

// ---- faithful fp32 distance (selection on RAW fp32 coords) ---------------
__device__ __forceinline__ float norm2_ref(float x, float y, float z) {
    return __fadd_rn(__fadd_rn(__fmul_rn(x, x), __fmul_rn(y, y)), __fmul_rn(z, z));
}
__device__ __forceinline__ float dist_ref(float sa, float nb,
                                          float ax, float ay, float az,
                                          float bx, float by, float bz) {
    float dot = __fadd_rn(__fadd_rn(__fmul_rn(ax, bx), __fmul_rn(ay, by)),
                          __fmul_rn(az, bz));
    return __fsub_rn(__fadd_rn(sa, nb), __fmul_rn(2.f, dot));
}

// ---------------------------------------------------------------------------
// 3-NN, 4-range split + stable merge (selection identical to sequential
// strict-< scan: per-range stable insertion, merge prefers lower range on
// exact ties). 256 blocks x 64 queries; thread = (query, range-of-256).
// ---------------------------------------------------------------------------
__global__ __launch_bounds__(256) void nn3_kernel(
    const float* __restrict__ xyz1, const float* __restrict__ xyz2,
    int* __restrict__ idx3, float* __restrict__ w3)
{
    const int b = blockIdx.x >> 6;             // N2/64 = 64 blocks per batch
    const int q0 = (blockIdx.x & 63) << 6;     // 64 queries per block
    const int tid = threadIdx.x;
    const int ql = tid >> 2, r = tid & 3;
    const int n = q0 + ql;
    __shared__ float sx[N1], sy[N1], sz[N1], snb[N1];
    __shared__ float sd[64][4][3];
    __shared__ int   si[64][4][3];
    for (int i = tid; i < N1; i += 256) {
        const float* p = xyz1 + ((size_t)b * N1 + i) * 3;
        float x = p[0], y = p[1], z = p[2];
        sx[i] = x; sy[i] = y; sz[i] = z;
        snb[i] = norm2_ref(x, y, z);
    }
    __syncthreads();
    const float* pq = xyz2 + ((size_t)b * N2 + n) * 3;
    const float ax = pq[0], ay = pq[1], az = pq[2];
    const float sa = norm2_ref(ax, ay, az);
    float d0 = FLT_MAX, d1 = FLT_MAX, d2 = FLT_MAX;
    int i0 = 0, i1 = 0, i2 = 0;
    const int jb = r << 8;
    for (int jj = 0; jj < 256; ++jj) {
        int j = jb + jj;
        float dist = dist_ref(sa, snb[j], ax, ay, az, sx[j], sy[j], sz[j]);
        if (dist < d2) {
            if (dist < d1) {
                d2 = d1; i2 = i1;
                if (dist < d0) { d1 = d0; i1 = i0; d0 = dist; i0 = j; }
                else           { d1 = dist; i1 = j; }
            } else { d2 = dist; i2 = j; }
        }
    }
    sd[ql][r][0] = d0; sd[ql][r][1] = d1; sd[ql][r][2] = d2;
    si[ql][r][0] = i0; si[ql][r][1] = i1; si[ql][r][2] = i2;
    __syncthreads();
    if (r == 0) {
        int p0 = 0, p1 = 0, p2 = 0, p3 = 0;
        float md[3]; int mi[3];
        for (int o = 0; o < 3; ++o) {
            float h0 = (p0 < 3) ? sd[ql][0][p0] : FLT_MAX;
            float h1 = (p1 < 3) ? sd[ql][1][p1] : FLT_MAX;
            float h2 = (p2 < 3) ? sd[ql][2][p2] : FLT_MAX;
            float h3 = (p3 < 3) ? sd[ql][3][p3] : FLT_MAX;
            int br = 0; float bd = h0;
            if (h1 < bd) { bd = h1; br = 1; }
            if (h2 < bd) { bd = h2; br = 2; }
            if (h3 < bd) { bd = h3; br = 3; }
            if (br == 0)      { mi[o] = si[ql][0][p0]; md[o] = h0; ++p0; }
            else if (br == 1) { mi[o] = si[ql][1][p1]; md[o] = h1; ++p1; }
            else if (br == 2) { mi[o] = si[ql][2][p2]; md[o] = h2; ++p2; }
            else              { mi[o] = si[ql][3][p3]; md[o] = h3; ++p3; }
        }
        float r0 = __fdiv_rn(1.f, __fadd_rn(md[0], 1e-8f));
        float r1 = __fdiv_rn(1.f, __fadd_rn(md[1], 1e-8f));
        float r2 = __fdiv_rn(1.f, __fadd_rn(md[2], 1e-8f));
        float s  = __fadd_rn(__fadd_rn(r0, r1), r2);
        size_t o = ((size_t)b * N2 + n) * 3;
        idx3[o] = mi[0]; idx3[o + 1] = mi[1]; idx3[o + 2] = mi[2];
        w3[o]     = __fdiv_rn(r0, s);
        w3[o + 1] = __fdiv_rn(r1, s);
        w3[o + 2] = __fdiv_rn(r2, s);
    }
}

// feats[bn,c] = bf16r( bf16r(fp32_sum w_i*f1_i) + f2 )  (unchanged)
__global__ __launch_bounds__(256) void interp_kernel(
    const float* __restrict__ f1, const int* __restrict__ idx3,
    const float* __restrict__ w3, float* __restrict__ feats)
{
    const int bn = blockIdx.x;
    const int b = bn >> 12;
    const int c = threadIdx.x;
    size_t o = (size_t)bn * 3;
    int i0 = idx3[o], i1 = idx3[o + 1], i2 = idx3[o + 2];
    float w0 = w3[o], w1 = w3[o + 1], w2 = w3[o + 2];
    const float* f1b = f1 + (size_t)b * N1 * 256;
    float itp = w0 * f1b[(size_t)i0 * 256 + c]
              + w1 * f1b[(size_t)i1 * 256 + c]
              + w2 * f1b[(size_t)i2 * 256 + c];
    feats[(size_t)bn * 256 + c] = bf16r(bf16r(itp) + feats[(size_t)bn * 256 + c]);
}

// ---------------------------------------------------------------------------
// KNN top-16 (unchanged — bit-identical selection)
// ---------------------------------------------------------------------------
__global__ __launch_bounds__(256) void knn_kernel(
    const float* __restrict__ xyz2, int* __restrict__ knn_out)
{
    const int b = blockIdx.x >> 6;
    const int q0 = (blockIdx.x & 63) << 6;
    const int tid = threadIdx.x;
    const int ql = tid >> 2, r = tid & 3;
    const int n = q0 + ql;
    __shared__ float sx[N2], sy[N2], sz[N2], sn[N2];
    __shared__ float sd[64][4][16];
    __shared__ int   si[64][4][16];
    for (int i = tid; i < N2; i += 256) {
        const float* p = xyz2 + ((size_t)b * N2 + i) * 3;
        float x = p[0], y = p[1], z = p[2];
        sx[i] = x; sy[i] = y; sz[i] = z;
        sn[i] = norm2_ref(x, y, z);
    }
    __syncthreads();
    const float ax = sx[n], ay = sy[n], az = sz[n];
    const float sa = sn[n];
    float d[16]; int id[16];
#pragma unroll
    for (int s = 0; s < 16; ++s) { d[s] = FLT_MAX; id[s] = 0; }
    const int jbase = r << 10;
    for (int jj = 0; jj < 1024; ++jj) {
        int j = jbase + jj;
        float dist = dist_ref(sa, sn[j], ax, ay, az, sx[j], sy[j], sz[j]);
        if (dist < d[15]) {
#pragma unroll
            for (int s = 15; s >= 0; --s) {
                bool shift = (s > 0) && (dist < d[s - 1]);
                bool place = (dist < d[s]) && !shift;
                float nd = shift ? d[s - 1] : (place ? dist : d[s]);
                int   ni = shift ? id[s - 1] : (place ? j : id[s]);
                d[s] = nd; id[s] = ni;
            }
        }
    }
#pragma unroll
    for (int s = 0; s < 16; ++s) { sd[ql][r][s] = d[s]; si[ql][r][s] = id[s]; }
    __syncthreads();
    if (r == 0) {
        int p0 = 0, p1 = 0, p2 = 0, p3 = 0;
        size_t ob = ((size_t)b * N2 + n) * 16;
        for (int o = 0; o < 16; ++o) {
            float h0 = (p0 < 16) ? sd[ql][0][p0] : FLT_MAX;
            float h1 = (p1 < 16) ? sd[ql][1][p1] : FLT_MAX;
            float h2 = (p2 < 16) ? sd[ql][2][p2] : FLT_MAX;
            float h3 = (p3 < 16) ? sd[ql][3][p3] : FLT_MAX;
            int br = 0; float bd = h0;
            if (h1 < bd) { bd = h1; br = 1; }
            if (h2 < bd) { bd = h2; br = 2; }
            if (h3 < bd) { bd = h3; br = 3; }
            int bi;
            if (br == 0)      { bi = si[ql][0][p0]; ++p0; }
            else if (br == 1) { bi = si[ql][1][p1]; ++p1; }
            else if (br == 2) { bi = si[ql][2][p2]; ++p2; }
            else              { bi = si[ql][3][p3]; ++p3; }
            knn_out[ob + o] = bi;
        }
    }
}

// ---------------------------------------------------------------------------
// MFMA attention, 4 points per block. Per-point arithmetic bit-identical to
// round 14 (same MFMA kb-order per chain, same rounding points, same softmax).
// B-fragments loaded once per kb and reused across the 4 points (L2 traffic /4).
// ---------------------------------------------------------------------------
__global__ __launch_bounds__(256) void attn_mfma4(
    const float* __restrict__ xyz2, const float* __restrict__ qg,
    const float* __restrict__ kg, const float* __restrict__ vg,
    const int* __restrict__ knn,
    const float* __restrict__ d1w, const float* __restrict__ d1b,
    const float* __restrict__ d2b, const float* __restrict__ g1b,
    const float* __restrict__ g2b,
    const unsigned short* __restrict__ Bd2,
    const unsigned short* __restrict__ Bg1,
    const unsigned short* __restrict__ Bg2,
    float* __restrict__ res)
{
    const int bn0 = blockIdx.x * PPB;
    const int b = bn0 >> 12;
    const int c = threadIdx.x;
    const int l = c & 63, wv_ = c >> 6;
    const int lr = l & 15, lg = l >> 4;

    __shared__ __align__(16) unsigned short phb[64][264];   // ph -> t -> h
    __shared__ __align__(16) unsigned short posb[64][264];  // pos, then a
    __shared__ int   knn_s[PPB][16];
    __shared__ float relx[PPB][16], rely[PPB][16], relz[PPB][16];

    if (c < 64) {
        int p = c >> 4, kk = c & 15;
        int idx = knn[(size_t)(bn0 + p) * 16 + kk];
        knn_s[p][kk] = idx;
        const float* pq = xyz2 + (size_t)(bn0 + p) * 3;
        const float* pk = xyz2 + ((size_t)b * N2 + idx) * 3;
        relx[p][kk] = bf16r(pq[0] - pk[0]);
        rely[p][kk] = bf16r(pq[1] - pk[1]);
        relz[p][kk] = bf16r(pq[2] - pk[2]);
    }
    __syncthreads();

    const size_t basebc = (size_t)b * N2 * 256;

    // ph[p][kk][c] = relu(bf16r(rel @ d1w + d1b))  (identical chain)
    {
        float w0 = bf16r(d1w[c]), w1 = bf16r(d1w[256 + c]), w2 = bf16r(d1w[512 + c]);
        float bb = d1b[c];
#pragma unroll
        for (int p = 0; p < PPB; ++p)
#pragma unroll
            for (int kk = 0; kk < 16; ++kk) {
                float v = fmaf(relx[p][kk], w0, fmaf(rely[p][kk], w1, fmaf(relz[p][kk], w2, bb)));
                phb[p * 16 + kk][c] = f2bu(fmaxf(bf16r(v), 0.f));
            }
    }
    __syncthreads();

    // ---- pos chain ----
    f32x4 acc[PPB][4];
#pragma unroll
    for (int p = 0; p < PPB; ++p)
#pragma unroll
        for (int t = 0; t < 4; ++t) acc[p][t] = (f32x4){0.f, 0.f, 0.f, 0.f};
    for (int kb = 0; kb < 8; ++kb) {
        bf16x8 bfr[4];
#pragma unroll
        for (int t = 0; t < 4; ++t)
            bfr[t] = *(const bf16x8*)&Bd2[((size_t)(kb * 16 + wv_ * 4 + t) * 64 + l) * 8];
#pragma unroll
        for (int p = 0; p < PPB; ++p) {
            bf16x8 af = *(const bf16x8*)&phb[p * 16 + lr][kb * 32 + lg * 8];
#pragma unroll
            for (int t = 0; t < 4; ++t)
                acc[p][t] = __builtin_amdgcn_mfma_f32_16x16x32_bf16(af, bfr[t], acc[p][t], 0, 0, 0);
        }
    }
#pragma unroll
    for (int p = 0; p < PPB; ++p)
#pragma unroll
        for (int t = 0; t < 4; ++t) {
            int col = (wv_ * 4 + t) * 16 + lr;
            float bb = d2b[col];
#pragma unroll
            for (int r = 0; r < 4; ++r)
                posb[p * 16 + lg * 4 + r][col] = f2bu(bf16r(acc[p][t][r] + bb));
        }
    __syncthreads();

    // t = bf16r(bf16r(q - kf) + pos)  (kf loaded inline; identical values)
    float posr[PPB][16];
    float qv[PPB];
#pragma unroll
    for (int p = 0; p < PPB; ++p) qv[p] = qg[(size_t)(bn0 + p) * 256 + c];
#pragma unroll
    for (int p = 0; p < PPB; ++p)
#pragma unroll
        for (int kk = 0; kk < 16; ++kk) posr[p][kk] = bu2f(posb[p * 16 + kk][c]);
#pragma unroll
    for (int p = 0; p < PPB; ++p)
#pragma unroll
        for (int kk = 0; kk < 16; ++kk) {
            float kfv = kg[basebc + (size_t)knn_s[p][kk] * 256 + c];
            phb[p * 16 + kk][c] = f2bu(bf16r(bf16r(qv[p] - kfv) + posr[p][kk]));
        }
    __syncthreads();

    // ---- h chain ----
#pragma unroll
    for (int p = 0; p < PPB; ++p)
#pragma unroll
        for (int t = 0; t < 4; ++t) acc[p][t] = (f32x4){0.f, 0.f, 0.f, 0.f};
    for (int kb = 0; kb < 8; ++kb) {
        bf16x8 bfr[4];
#pragma unroll
        for (int t = 0; t < 4; ++t)
            bfr[t] = *(const bf16x8*)&Bg1[((size_t)(kb * 16 + wv_ * 4 + t) * 64 + l) * 8];
#pragma unroll
        for (int p = 0; p < PPB; ++p) {
            bf16x8 af = *(const bf16x8*)&phb[p * 16 + lr][kb * 32 + lg * 8];
#pragma unroll
            for (int t = 0; t < 4; ++t)
                acc[p][t] = __builtin_amdgcn_mfma_f32_16x16x32_bf16(af, bfr[t], acc[p][t], 0, 0, 0);
        }
    }
    __syncthreads();   // all t reads done before phb overwrite
#pragma unroll
    for (int p = 0; p < PPB; ++p)
#pragma unroll
        for (int t = 0; t < 4; ++t) {
            int col = (wv_ * 4 + t) * 16 + lr;
            float bb = g1b[col];
#pragma unroll
            for (int r = 0; r < 4; ++r)
                phb[p * 16 + lg * 4 + r][col] = f2bu(fmaxf(bf16r(acc[p][t][r] + bb), 0.f));
        }
    __syncthreads();

    // ---- a chain ----
#pragma unroll
    for (int p = 0; p < PPB; ++p)
#pragma unroll
        for (int t = 0; t < 4; ++t) acc[p][t] = (f32x4){0.f, 0.f, 0.f, 0.f};
    for (int kb = 0; kb < 8; ++kb) {
        bf16x8 bfr[4];
#pragma unroll
        for (int t = 0; t < 4; ++t)
            bfr[t] = *(const bf16x8*)&Bg2[((size_t)(kb * 16 + wv_ * 4 + t) * 64 + l) * 8];
#pragma unroll
        for (int p = 0; p < PPB; ++p) {
            bf16x8 af = *(const bf16x8*)&phb[p * 16 + lr][kb * 32 + lg * 8];
#pragma unroll
            for (int t = 0; t < 4; ++t)
                acc[p][t] = __builtin_amdgcn_mfma_f32_16x16x32_bf16(af, bfr[t], acc[p][t], 0, 0, 0);
        }
    }
#pragma unroll
    for (int p = 0; p < PPB; ++p)
#pragma unroll
        for (int t = 0; t < 4; ++t) {
            int col = (wv_ * 4 + t) * 16 + lr;
            float bb = g2b[col];
#pragma unroll
            for (int r = 0; r < 4; ++r)
                posb[p * 16 + lg * 4 + r][col] = f2bu(bf16r(acc[p][t][r] + bb));
        }
    __syncthreads();

    // softmax + weighted sum per point (identical per-thread chain)
#pragma unroll
    for (int p = 0; p < PPB; ++p) {
        float av[16];
#pragma unroll
        for (int kk = 0; kk < 16; ++kk) av[kk] = bu2f(posb[p * 16 + kk][c]) * 0.0625f;
        float m = av[0];
#pragma unroll
        for (int kk = 1; kk < 16; ++kk) m = fmaxf(m, av[kk]);
        float e[16];
        float s = 0.f;
#pragma unroll
        for (int kk = 0; kk < 16; ++kk) {
            e[kk] = bf16r(expf(av[kk] - m));
            s += e[kk];
        }
#pragma unroll
        for (int kk = 0; kk < 16; ++kk) e[kk] = bf16r(e[kk] / s);
        float rr = 0.f;
#pragma unroll
        for (int kk = 0; kk < 16; ++kk) {
            float vfv = vg[basebc + (size_t)knn_s[p][kk] * 256 + c];
            float vp = bf16r(vfv + posr[p][kk]);
            rr = fmaf(e[kk], vp, rr);
        }
        res[(size_t)(bn0 + p) * 256 + c] = bf16r(rr);
    }
}

// ---------------------------------------------------------------------------
extern "C" void kernel_launch(void* const* d_in, const int* in_sizes, int n_in,
                              void* d_out, int out_size, void* d_ws, size_t ws_size,
                              hipStream_t stream)
{
    const float* xyz1     = (const float*)d_in[0];
    const float* points1  = (const float*)d_in[1];
    const float* xyz2     = (const float*)d_in[2];
    const float* points2  = (const float*)d_in[3];
    const float* up_w1    = (const float*)d_in[4];
    const float* up_b1    = (const float*)d_in[5];
    const float* up_w2    = (const float*)d_in[6];
    const float* up_b2    = (const float*)d_in[7];
    const float* fc1_w    = (const float*)d_in[8];
    const float* fc1_b    = (const float*)d_in[9];
    const float* fc2_w    = (const float*)d_in[10];
    const float* fc2_b    = (const float*)d_in[11];
    const float* delta_w1 = (const float*)d_in[12];
    const float* delta_b1 = (const float*)d_in[13];
    const float* delta_w2 = (const float*)d_in[14];
    const float* delta_b2 = (const float*)d_in[15];
    const float* gamma_w1 = (const float*)d_in[16];
    const float* gamma_b1 = (const float*)d_in[17];
    const float* gamma_w2 = (const float*)d_in[18];
    const float* gamma_b2 = (const float*)d_in[19];
    const float* wq       = (const float*)d_in[20];
    const float* wk       = (const float*)d_in[21];
    const float* wv       = (const float*)d_in[22];

    float* ws = (float*)d_ws;
    float* f1    = ws;
    float* feats = f1 + (size_t)BB * N1 * 256;
    float* x     = feats + (size_t)BB * N2 * 256;
    float* qb    = x + (size_t)BB * N2 * 256;
    float* kb    = qb + (size_t)BB * N2 * 256;
    float* vb    = kb + (size_t)BB * N2 * 256;
    int*   idx3  = (int*)(vb + (size_t)BB * N2 * 256);
    float* w3    = (float*)(idx3 + (size_t)BB * N2 * 3);
    int*   knn   = (int*)(w3 + (size_t)BB * N2 * 3);
    unsigned short* Bd2  = (unsigned short*)(knn + (size_t)BB * N2 * 16);
    unsigned short* Bg1  = Bd2 + 65536;
    unsigned short* Bg2  = Bg1 + 65536;
    unsigned short* Bup1 = Bg2 + 65536;       // 512x256 -> 131072
    unsigned short* Bup2 = Bup1 + 131072;
    unsigned short* Bfc1 = Bup2 + 65536;
    unsigned short* Bfc2 = Bfc1 + 65536;
    unsigned short* Bq   = Bfc2 + 65536;
    unsigned short* Bk   = Bq + 65536;
    unsigned short* Bv   = Bk + 65536;
    float* resb = x;   // x dead after q/k/v

    float* out = (float*)d_out;
    hipMemcpyAsync(out, xyz2, (size_t)BB * N2 * 3 * sizeof(float),
                   hipMemcpyDeviceToDevice, stream);

    const float BN = (float)(1.0 / sqrt(1.0 + 1e-5));

    // all weight swizzles in one launch
    SwzArgs sa;
    sa.W[0] = up_w1;    sa.B[0] = Bup1; sa.K[0] = CIN;
    sa.W[1] = up_w2;    sa.B[1] = Bup2; sa.K[1] = CC;
    sa.W[2] = fc1_w;    sa.B[2] = Bfc1; sa.K[2] = CC;
    sa.W[3] = fc2_w;    sa.B[3] = Bfc2; sa.K[3] = CC;
    sa.W[4] = wq;       sa.B[4] = Bq;   sa.K[4] = CC;
    sa.W[5] = wk;       sa.B[5] = Bk;   sa.K[5] = CC;
    sa.W[6] = wv;       sa.B[6] = Bv;   sa.K[6] = CC;
    sa.W[7] = delta_w2; sa.B[7] = Bd2;  sa.K[7] = CC;
    sa.W[8] = gamma_w1; sa.B[8] = Bg1;  sa.K[8] = CC;
    sa.W[9] = gamma_w2; sa.B[9] = Bg2;  sa.K[9] = CC;
    swizzle_all<<<dim3(64, 10), 256, 0, stream>>>(sa);

    // f2 = relu(bf16(points2) @ bf16(up_w2) * bn) -> feats   [512 blocks]
    gemm_mfma<CC, 8, true, true, false><<<BB * N2 / 64 * 2, 256, 0, stream>>>(
        points2, Bup2, up_b2, nullptr, BN, feats);
    // f1 = relu(bf16(points1) @ bf16(up_w1) * bn)            [256 blocks]
    gemm_mfma<CIN, 4, true, true, false><<<BB * N1 / 64 * 4, 256, 0, stream>>>(
        points1, Bup1, up_b1, nullptr, BN, f1);
    // selection on raw fp32 coords (bit-identical)
    nn3_kernel<<<BB * 64, 256, 0, stream>>>(xyz1, xyz2, idx3, w3);
    interp_kernel<<<BB * N2, 256, 0, stream>>>(f1, idx3, w3, feats);
    // x = bf16r(feats @ bf16(fc1_w))                         [512 blocks]
    gemm_mfma<CC, 8, false, false, false><<<BB * N2 / 64 * 2, 256, 0, stream>>>(
        feats, Bfc1, fc1_b, nullptr, 1.f, x);
    // fused q/k/v                                            [512 blocks]
    qkv_mfma<<<BB * N2 / 64 * 2, 256, 0, stream>>>(x, Bq, Bk, Bv, qb, kb, vb);
    knn_kernel<<<BB * 64, 256, 0, stream>>>(xyz2, knn);
    // MFMA attention, 4 points/block                         [4096 blocks]
    attn_mfma4<<<BB * N2 / PPB, 256, 0, stream>>>(xyz2, qb, kb, vb, knn,
                                                  delta_w1, delta_b1, delta_b2, gamma_b1, gamma_b2,
                                                  Bd2, Bg1, Bg2, resb);
    // out1 = bf16r(bf16r(resb @ bf16(fc2_w)) + feats)        [512 blocks]
    gemm_mfma<CC, 8, false, false, true><<<BB * N2 / 64 * 2, 256, 0, stream>>>(
        resb, Bfc2, fc2_b, feats, 1.f, out + (size_t)BB * N2 * 3);
}

// Round 16
// 694.534 us; speedup vs baseline: 1.2307x; 1.2307x over previous
//
#include <hip/hip_runtime.h>
#include <hip/hip_bf16.h>
#include <math.h>
#include <float.h>

#define BB   4
#define N1   1024
#define N2   4096
#define CIN  512
#define CC   256
#define DM   256
#define KNNK 16

typedef __attribute__((ext_vector_type(8))) short bf16x8;
typedef __attribute__((ext_vector_type(4))) float f32x4;

__device__ __forceinline__ float bf16r(float x) {
    return __bfloat162float(__float2bfloat16(x));
}
__device__ __forceinline__ unsigned short f2bu(float x) {
    __hip_bfloat16 h = __float2bfloat16(x);
    return *reinterpret_cast<unsigned short*>(&h);
}
__device__ __forceinline__ float bu2f(unsigned short u) {
    __hip_bfloat16 h = *reinterpret_cast<__hip_bfloat16*>(&u);
    return __bfloat162float(h);
}

// ---------------------------------------------------------------------------
// All 10 weight swizzles in one launch.
// B[((kb*16+tile)*64+l)*8 + i] = bf16(W[kb*32+(l>>4)*8+i][tile*16+(l&15)])
// ---------------------------------------------------------------------------
struct SwzArgs {
    const float* W[10];
    unsigned short* B[10];
    int K[10];
};
__global__ __launch_bounds__(256) void swizzle_all(SwzArgs a)
{
    int m = blockIdx.y;
    int idx = blockIdx.x * 256 + threadIdx.x;
    int total = (a.K[m] >> 5) << 10;
    if (idx >= total) return;
    const float* W = a.W[m];
    unsigned short* B = a.B[m];
    int l = idx & 63;
    int tile = (idx >> 6) & 15;
    int kb = idx >> 10;
    int col = tile * 16 + (l & 15);
    int k0 = kb * 32 + ((l >> 4) << 3);
#pragma unroll
    for (int i = 0; i < 8; ++i)
        B[(size_t)idx * 8 + i] = f2bu(W[(size_t)(k0 + i) * 256 + col]);
}

// ---------------------------------------------------------------------------
// MFMA GEMM, N-split (bit-identical arithmetic; bf16r(bf16r(x)) folded)
// ---------------------------------------------------------------------------
template<int KD, int NT, bool RELU, bool BN_, bool RESID>
__global__ __launch_bounds__(256) void gemm_mfma(
    const float* __restrict__ X, const unsigned short* __restrict__ Bw,
    const float* __restrict__ bias, const float* __restrict__ resid,
    float scale, float* __restrict__ Y)
{
    const int NSPLIT = 16 / NT;
    const int c = threadIdx.x;
    const int l = c & 63, wv_ = c >> 6;
    const int lr = l & 15, lg = l >> 4;
    const int row0 = (blockIdx.x / NSPLIT) * 64;
    const int tb = (blockIdx.x % NSPLIT) * NT;
    __shared__ __align__(16) unsigned short As[64][72];

    f32x4 acc[NT];
#pragma unroll
    for (int t = 0; t < NT; ++t) acc[t] = (f32x4){0.f, 0.f, 0.f, 0.f};

    const int rs = c >> 2, c0 = (c & 3) * 16;
    for (int ks = 0; ks < KD / 64; ++ks) {
        const float* src = X + (size_t)(row0 + rs) * KD + ks * 64 + c0;
#pragma unroll
        for (int i = 0; i < 16; i += 4) {
            float4 v = *(const float4*)(src + i);
            As[rs][c0 + i + 0] = f2bu(v.x);
            As[rs][c0 + i + 1] = f2bu(v.y);
            As[rs][c0 + i + 2] = f2bu(v.z);
            As[rs][c0 + i + 3] = f2bu(v.w);
        }
        __syncthreads();
#pragma unroll
        for (int kbl = 0; kbl < 2; ++kbl) {
            int kb = ks * 2 + kbl;
            bf16x8 af = *(const bf16x8*)&As[wv_ * 16 + lr][kbl * 32 + lg * 8];
#pragma unroll
            for (int t = 0; t < NT; ++t) {
                bf16x8 bf = *(const bf16x8*)&Bw[((size_t)(kb * 16 + tb + t) * 64 + l) * 8];
                acc[t] = __builtin_amdgcn_mfma_f32_16x16x32_bf16(af, bf, acc[t], 0, 0, 0);
            }
        }
        __syncthreads();
    }
#pragma unroll
    for (int t = 0; t < NT; ++t) {
        int col = (tb + t) * 16 + lr;
        float bb = bias ? bias[col] : 0.f;
#pragma unroll
        for (int r = 0; r < 4; ++r) {
            size_t row = row0 + wv_ * 16 + lg * 4 + r;
            float v = bf16r(acc[t][r]);
            v = bf16r(v + bb);
            if (BN_) v = bf16r(v * scale);
            if (RELU) v = fmaxf(v, 0.f);
            if (RESID) v = bf16r(v + resid[row * 256 + col]);
            Y[row * 256 + col] = v;
        }
    }
}

// ---------------------------------------------------------------------------
// Fused q/k/v GEMM (bit-identical; double-round folded to single RNE)
// ---------------------------------------------------------------------------
__global__ __launch_bounds__(256) void qkv_mfma(
    const float* __restrict__ X,
    const unsigned short* __restrict__ Bq,
    const unsigned short* __restrict__ Bk,
    const unsigned short* __restrict__ Bv,
    float* __restrict__ Yq, float* __restrict__ Yk, float* __restrict__ Yv)
{
    const int NT = 8;
    const int c = threadIdx.x;
    const int l = c & 63, wv_ = c >> 6;
    const int lr = l & 15, lg = l >> 4;
    const int row0 = (blockIdx.x >> 1) * 64;
    const int tb = (blockIdx.x & 1) * NT;
    __shared__ __align__(16) unsigned short As[64][72];

    f32x4 aq[NT], ak[NT], av_[NT];
#pragma unroll
    for (int t = 0; t < NT; ++t) {
        aq[t] = (f32x4){0.f, 0.f, 0.f, 0.f};
        ak[t] = aq[t]; av_[t] = aq[t];
    }

    const int rs = c >> 2, c0 = (c & 3) * 16;
    for (int ks = 0; ks < CC / 64; ++ks) {
        const float* src = X + (size_t)(row0 + rs) * CC + ks * 64 + c0;
#pragma unroll
        for (int i = 0; i < 16; i += 4) {
            float4 v = *(const float4*)(src + i);
            As[rs][c0 + i + 0] = f2bu(v.x);
            As[rs][c0 + i + 1] = f2bu(v.y);
            As[rs][c0 + i + 2] = f2bu(v.z);
            As[rs][c0 + i + 3] = f2bu(v.w);
        }
        __syncthreads();
#pragma unroll
        for (int kbl = 0; kbl < 2; ++kbl) {
            int kb = ks * 2 + kbl;
            bf16x8 af = *(const bf16x8*)&As[wv_ * 16 + lr][kbl * 32 + lg * 8];
#pragma unroll
            for (int t = 0; t < NT; ++t) {
                size_t fo = ((size_t)(kb * 16 + tb + t) * 64 + l) * 8;
                bf16x8 bq = *(const bf16x8*)&Bq[fo];
                bf16x8 bk = *(const bf16x8*)&Bk[fo];
                bf16x8 bv = *(const bf16x8*)&Bv[fo];
                aq[t]  = __builtin_amdgcn_mfma_f32_16x16x32_bf16(af, bq, aq[t], 0, 0, 0);
                ak[t]  = __builtin_amdgcn_mfma_f32_16x16x32_bf16(af, bk, ak[t], 0, 0, 0);
                av_[t] = __builtin_amdgcn_mfma_f32_16x16x32_bf16(af, bv, av_[t], 0, 0, 0);
            }
        }
        __syncthreads();
    }
#pragma unroll
    for (int t = 0; t < NT; ++t) {
        int col = (tb + t) * 16 + lr;
#pragma unroll
        for (int r = 0; r < 4; ++r) {
            size_t row = row0 + wv_ * 16 + lg * 4 + r;
            Yq[row * 256 + col] = bf16r(aq[t][r]);   // == bf16r(bf16r(x))
            Yk[row * 256 + col] = bf16r(ak[t][r]);
            Yv[row * 256 + col] = bf16r(av_[t][r]);
        }
    }
}

// ---- faithful fp32 distance (selection on RAW fp32 coords) ---------------
__device__ __forceinline__ float norm2_ref(float x, float y, float z) {
    return __fadd_rn(__fadd_rn(__fmul_rn(x, x), __fmul_rn(y, y)), __fmul_rn(z, z));
}
__device__ __forceinline__ float dist_ref(float sa, float nb,
                                          float ax, float ay, float az,
                                          float bx, float by, float bz) {
    float dot = __fadd_rn(__fadd_rn(__fmul_rn(ax, bx), __fmul_rn(ay, by)),
                          __fmul_rn(az, bz));
    return __fsub_rn(__fadd_rn(sa, nb), __fmul_rn(2.f, dot));
}

// ---------------------------------------------------------------------------
// 3-NN + fused interpolation. Selection identical to round 14/15 (4-range
// split, stable strict-< insertion, merge prefers lower range). After the
// weights, the block applies the interp gather-add for its 64 queries with
// the identical rounding expression as the old interp_kernel.
// ---------------------------------------------------------------------------
__global__ __launch_bounds__(256) void nn3_interp_kernel(
    const float* __restrict__ xyz1, const float* __restrict__ xyz2,
    const float* __restrict__ f1, float* __restrict__ feats)
{
    const int b = blockIdx.x >> 6;             // 64 blocks per batch
    const int q0 = (blockIdx.x & 63) << 6;     // 64 queries per block
    const int tid = threadIdx.x;
    const int ql = tid >> 2, r = tid & 3;
    const int n = q0 + ql;
    __shared__ float sx[N1], sy[N1], sz[N1], snb[N1];
    __shared__ float sd[64][4][3];
    __shared__ int   si[64][4][3];
    __shared__ float sw[64][3];
    __shared__ int   sidx[64][3];
    for (int i = tid; i < N1; i += 256) {
        const float* p = xyz1 + ((size_t)b * N1 + i) * 3;
        float x = p[0], y = p[1], z = p[2];
        sx[i] = x; sy[i] = y; sz[i] = z;
        snb[i] = norm2_ref(x, y, z);
    }
    __syncthreads();
    const float* pq = xyz2 + ((size_t)b * N2 + n) * 3;
    const float ax = pq[0], ay = pq[1], az = pq[2];
    const float sa = norm2_ref(ax, ay, az);
    float d0 = FLT_MAX, d1 = FLT_MAX, d2 = FLT_MAX;
    int i0 = 0, i1 = 0, i2 = 0;
    const int jb = r << 8;
    for (int jj = 0; jj < 256; ++jj) {
        int j = jb + jj;
        float dist = dist_ref(sa, snb[j], ax, ay, az, sx[j], sy[j], sz[j]);
        if (dist < d2) {
            if (dist < d1) {
                d2 = d1; i2 = i1;
                if (dist < d0) { d1 = d0; i1 = i0; d0 = dist; i0 = j; }
                else           { d1 = dist; i1 = j; }
            } else { d2 = dist; i2 = j; }
        }
    }
    sd[ql][r][0] = d0; sd[ql][r][1] = d1; sd[ql][r][2] = d2;
    si[ql][r][0] = i0; si[ql][r][1] = i1; si[ql][r][2] = i2;
    __syncthreads();
    if (r == 0) {
        int p0 = 0, p1 = 0, p2 = 0, p3 = 0;
        float md[3]; int mi[3];
        for (int o = 0; o < 3; ++o) {
            float h0 = (p0 < 3) ? sd[ql][0][p0] : FLT_MAX;
            float h1 = (p1 < 3) ? sd[ql][1][p1] : FLT_MAX;
            float h2 = (p2 < 3) ? sd[ql][2][p2] : FLT_MAX;
            float h3 = (p3 < 3) ? sd[ql][3][p3] : FLT_MAX;
            int br = 0; float bd = h0;
            if (h1 < bd) { bd = h1; br = 1; }
            if (h2 < bd) { bd = h2; br = 2; }
            if (h3 < bd) { bd = h3; br = 3; }
            if (br == 0)      { mi[o] = si[ql][0][p0]; md[o] = h0; ++p0; }
            else if (br == 1) { mi[o] = si[ql][1][p1]; md[o] = h1; ++p1; }
            else if (br == 2) { mi[o] = si[ql][2][p2]; md[o] = h2; ++p2; }
            else              { mi[o] = si[ql][3][p3]; md[o] = h3; ++p3; }
        }
        float r0 = __fdiv_rn(1.f, __fadd_rn(md[0], 1e-8f));
        float r1 = __fdiv_rn(1.f, __fadd_rn(md[1], 1e-8f));
        float r2 = __fdiv_rn(1.f, __fadd_rn(md[2], 1e-8f));
        float s  = __fadd_rn(__fadd_rn(r0, r1), r2);
        sw[ql][0] = __fdiv_rn(r0, s);
        sw[ql][1] = __fdiv_rn(r1, s);
        sw[ql][2] = __fdiv_rn(r2, s);
        sidx[ql][0] = mi[0]; sidx[ql][1] = mi[1]; sidx[ql][2] = mi[2];
    }
    __syncthreads();
    // fused interp: identical expression to the old interp_kernel
    const float* f1b = f1 + (size_t)b * N1 * 256;
    for (int p = 0; p < 64; ++p) {
        int bn = (b << 12) + q0 + p;
        float w0 = sw[p][0], w1 = sw[p][1], w2 = sw[p][2];
        int j0 = sidx[p][0], j1 = sidx[p][1], j2 = sidx[p][2];
        float itp = w0 * f1b[(size_t)j0 * 256 + tid]
                  + w1 * f1b[(size_t)j1 * 256 + tid]
                  + w2 * f1b[(size_t)j2 * 256 + tid];
        feats[(size_t)bn * 256 + tid] = bf16r(bf16r(itp) + feats[(size_t)bn * 256 + tid]);
    }
}

// ---------------------------------------------------------------------------
// KNN top-16 (unchanged — bit-identical selection)
// ---------------------------------------------------------------------------
__global__ __launch_bounds__(256) void knn_kernel(
    const float* __restrict__ xyz2, int* __restrict__ knn_out)
{
    const int b = blockIdx.x >> 6;
    const int q0 = (blockIdx.x & 63) << 6;
    const int tid = threadIdx.x;
    const int ql = tid >> 2, r = tid & 3;
    const int n = q0 + ql;
    __shared__ float sx[N2], sy[N2], sz[N2], sn[N2];
    __shared__ float sd[64][4][16];
    __shared__ int   si[64][4][16];
    for (int i = tid; i < N2; i += 256) {
        const float* p = xyz2 + ((size_t)b * N2 + i) * 3;
        float x = p[0], y = p[1], z = p[2];
        sx[i] = x; sy[i] = y; sz[i] = z;
        sn[i] = norm2_ref(x, y, z);
    }
    __syncthreads();
    const float ax = sx[n], ay = sy[n], az = sz[n];
    const float sa = sn[n];
    float d[16]; int id[16];
#pragma unroll
    for (int s = 0; s < 16; ++s) { d[s] = FLT_MAX; id[s] = 0; }
    const int jbase = r << 10;
    for (int jj = 0; jj < 1024; ++jj) {
        int j = jbase + jj;
        float dist = dist_ref(sa, sn[j], ax, ay, az, sx[j], sy[j], sz[j]);
        if (dist < d[15]) {
#pragma unroll
            for (int s = 15; s >= 0; --s) {
                bool shift = (s > 0) && (dist < d[s - 1]);
                bool place = (dist < d[s]) && !shift;
                float nd = shift ? d[s - 1] : (place ? dist : d[s]);
                int   ni = shift ? id[s - 1] : (place ? j : id[s]);
                d[s] = nd; id[s] = ni;
            }
        }
    }
#pragma unroll
    for (int s = 0; s < 16; ++s) { sd[ql][r][s] = d[s]; si[ql][r][s] = id[s]; }
    __syncthreads();
    if (r == 0) {
        int p0 = 0, p1 = 0, p2 = 0, p3 = 0;
        size_t ob = ((size_t)b * N2 + n) * 16;
        for (int o = 0; o < 16; ++o) {
            float h0 = (p0 < 16) ? sd[ql][0][p0] : FLT_MAX;
            float h1 = (p1 < 16) ? sd[ql][1][p1] : FLT_MAX;
            float h2 = (p2 < 16) ? sd[ql][2][p2] : FLT_MAX;
            float h3 = (p3 < 16) ? sd[ql][3][p3] : FLT_MAX;
            int br = 0; float bd = h0;
            if (h1 < bd) { bd = h1; br = 1; }
            if (h2 < bd) { bd = h2; br = 2; }
            if (h3 < bd) { bd = h3; br = 3; }
            int bi;
            if (br == 0)      { bi = si[ql][0][p0]; ++p0; }
            else if (br == 1) { bi = si[ql][1][p1]; ++p1; }
            else if (br == 2) { bi = si[ql][2][p2]; ++p2; }
            else              { bi = si[ql][3][p3]; ++p3; }
            knn_out[ob + o] = bi;
        }
    }
}

// ---------------------------------------------------------------------------
// MFMA attention, 1 point per block (round-14 version, 303 us, occupancy 45%).
// Value-identical cvt folds: f2bu(bf16r(x)) -> f2bu(x); relu/RNE commute.
// ---------------------------------------------------------------------------
__global__ __launch_bounds__(256) void attn_mfma(
    const float* __restrict__ xyz2, const float* __restrict__ qg,
    const float* __restrict__ kg, const float* __restrict__ vg,
    const int* __restrict__ knn,
    const float* __restrict__ d1w, const float* __restrict__ d1b,
    const float* __restrict__ d2b, const float* __restrict__ g1b,
    const float* __restrict__ g2b,
    const unsigned short* __restrict__ Bd2,
    const unsigned short* __restrict__ Bg1,
    const unsigned short* __restrict__ Bg2,
    float* __restrict__ res)
{
    const int bn = blockIdx.x;
    const int b = bn >> 12;
    const int c = threadIdx.x;
    const int l = c & 63, wv_ = c >> 6;
    const int lr = l & 15, lg = l >> 4;

    __shared__ __align__(16) unsigned short phb[16][264];
    __shared__ __align__(16) unsigned short posb[16][264];
    __shared__ int   knn_s[16];
    __shared__ float relx[16], rely[16], relz[16];

    if (c < 16) {
        int idx = knn[(size_t)bn * 16 + c];
        knn_s[c] = idx;
        const float* pq = xyz2 + (size_t)bn * 3;
        const float* pk = xyz2 + ((size_t)b * N2 + idx) * 3;
        relx[c] = bf16r(pq[0] - pk[0]);
        rely[c] = bf16r(pq[1] - pk[1]);
        relz[c] = bf16r(pq[2] - pk[2]);
    }
    __syncthreads();

    const size_t basebc = (size_t)b * N2 * 256;
    float kf[16], vf[16];
#pragma unroll
    for (int kk = 0; kk < 16; ++kk) {
        int row = knn_s[kk];
        kf[kk] = kg[basebc + (size_t)row * 256 + c];
        vf[kk] = vg[basebc + (size_t)row * 256 + c];
    }
    float qv = qg[(size_t)bn * 256 + c];

    // ph = relu(bf16r(rel @ d1w + d1b))   [f2bu(max(v,0)) == f2bu(max(bf16r(v),0))]
    {
        float w0 = bf16r(d1w[c]), w1 = bf16r(d1w[256 + c]), w2 = bf16r(d1w[512 + c]);
        float bb = d1b[c];
#pragma unroll
        for (int kk = 0; kk < 16; ++kk) {
            float v = fmaf(relx[kk], w0, fmaf(rely[kk], w1, fmaf(relz[kk], w2, bb)));
            phb[kk][c] = f2bu(fmaxf(v, 0.f));
        }
    }
    __syncthreads();

    f32x4 a0 = {0.f,0.f,0.f,0.f}, a1 = a0, a2 = a0, a3 = a0;
    for (int kb = 0; kb < 8; ++kb) {
        bf16x8 af = *(const bf16x8*)&phb[lr][kb * 32 + lg * 8];
        bf16x8 b0 = *(const bf16x8*)&Bd2[((size_t)(kb * 16 + wv_ * 4 + 0) * 64 + l) * 8];
        bf16x8 b1 = *(const bf16x8*)&Bd2[((size_t)(kb * 16 + wv_ * 4 + 1) * 64 + l) * 8];
        bf16x8 b2 = *(const bf16x8*)&Bd2[((size_t)(kb * 16 + wv_ * 4 + 2) * 64 + l) * 8];
        bf16x8 b3 = *(const bf16x8*)&Bd2[((size_t)(kb * 16 + wv_ * 4 + 3) * 64 + l) * 8];
        a0 = __builtin_amdgcn_mfma_f32_16x16x32_bf16(af, b0, a0, 0, 0, 0);
        a1 = __builtin_amdgcn_mfma_f32_16x16x32_bf16(af, b1, a1, 0, 0, 0);
        a2 = __builtin_amdgcn_mfma_f32_16x16x32_bf16(af, b2, a2, 0, 0, 0);
        a3 = __builtin_amdgcn_mfma_f32_16x16x32_bf16(af, b3, a3, 0, 0, 0);
    }
#pragma unroll
    for (int t = 0; t < 4; ++t) {
        const f32x4 av4 = (t == 0) ? a0 : (t == 1) ? a1 : (t == 2) ? a2 : a3;
        int col = (wv_ * 4 + t) * 16 + lr;
        float bb = d2b[col];
#pragma unroll
        for (int r = 0; r < 4; ++r)
            posb[lg * 4 + r][col] = f2bu(av4[r] + bb);   // == f2bu(bf16r(...))
    }
    __syncthreads();

    float posr[16];
#pragma unroll
    for (int kk = 0; kk < 16; ++kk) posr[kk] = bu2f(posb[kk][c]);
#pragma unroll
    for (int kk = 0; kk < 16; ++kk)
        phb[kk][c] = f2bu(bf16r(qv - kf[kk]) + posr[kk]);
    __syncthreads();

    a0 = (f32x4){0.f,0.f,0.f,0.f}; a1 = a0; a2 = a0; a3 = a0;
    for (int kb = 0; kb < 8; ++kb) {
        bf16x8 af = *(const bf16x8*)&phb[lr][kb * 32 + lg * 8];
        bf16x8 b0 = *(const bf16x8*)&Bg1[((size_t)(kb * 16 + wv_ * 4 + 0) * 64 + l) * 8];
        bf16x8 b1 = *(const bf16x8*)&Bg1[((size_t)(kb * 16 + wv_ * 4 + 1) * 64 + l) * 8];
        bf16x8 b2 = *(const bf16x8*)&Bg1[((size_t)(kb * 16 + wv_ * 4 + 2) * 64 + l) * 8];
        bf16x8 b3 = *(const bf16x8*)&Bg1[((size_t)(kb * 16 + wv_ * 4 + 3) * 64 + l) * 8];
        a0 = __builtin_amdgcn_mfma_f32_16x16x32_bf16(af, b0, a0, 0, 0, 0);
        a1 = __builtin_amdgcn_mfma_f32_16x16x32_bf16(af, b1, a1, 0, 0, 0);
        a2 = __builtin_amdgcn_mfma_f32_16x16x32_bf16(af, b2, a2, 0, 0, 0);
        a3 = __builtin_amdgcn_mfma_f32_16x16x32_bf16(af, b3, a3, 0, 0, 0);
    }
    __syncthreads();
#pragma unroll
    for (int t = 0; t < 4; ++t) {
        const f32x4 av4 = (t == 0) ? a0 : (t == 1) ? a1 : (t == 2) ? a2 : a3;
        int col = (wv_ * 4 + t) * 16 + lr;
        float bb = g1b[col];
#pragma unroll
        for (int r = 0; r < 4; ++r)
            phb[lg * 4 + r][col] = f2bu(fmaxf(av4[r] + bb, 0.f));
    }
    __syncthreads();

    a0 = (f32x4){0.f,0.f,0.f,0.f}; a1 = a0; a2 = a0; a3 = a0;
    for (int kb = 0; kb < 8; ++kb) {
        bf16x8 af = *(const bf16x8*)&phb[lr][kb * 32 + lg * 8];
        bf16x8 b0 = *(const bf16x8*)&Bg2[((size_t)(kb * 16 + wv_ * 4 + 0) * 64 + l) * 8];
        bf16x8 b1 = *(const bf16x8*)&Bg2[((size_t)(kb * 16 + wv_ * 4 + 1) * 64 + l) * 8];
        bf16x8 b2 = *(const bf16x8*)&Bg2[((size_t)(kb * 16 + wv_ * 4 + 2) * 64 + l) * 8];
        bf16x8 b3 = *(const bf16x8*)&Bg2[((size_t)(kb * 16 + wv_ * 4 + 3) * 64 + l) * 8];
        a0 = __builtin_amdgcn_mfma_f32_16x16x32_bf16(af, b0, a0, 0, 0, 0);
        a1 = __builtin_amdgcn_mfma_f32_16x16x32_bf16(af, b1, a1, 0, 0, 0);
        a2 = __builtin_amdgcn_mfma_f32_16x16x32_bf16(af, b2, a2, 0, 0, 0);
        a3 = __builtin_amdgcn_mfma_f32_16x16x32_bf16(af, b3, a3, 0, 0, 0);
    }
#pragma unroll
    for (int t = 0; t < 4; ++t) {
        const f32x4 av4 = (t == 0) ? a0 : (t == 1) ? a1 : (t == 2) ? a2 : a3;
        int col = (wv_ * 4 + t) * 16 + lr;
        float bb = g2b[col];
#pragma unroll
        for (int r = 0; r < 4; ++r)
            posb[lg * 4 + r][col] = f2bu(av4[r] + bb);
    }
    __syncthreads();

    float av[16];
#pragma unroll
    for (int kk = 0; kk < 16; ++kk) av[kk] = bu2f(posb[kk][c]) * 0.0625f;
    float m = av[0];
#pragma unroll
    for (int kk = 1; kk < 16; ++kk) m = fmaxf(m, av[kk]);
    float e[16];
    float s = 0.f;
#pragma unroll
    for (int kk = 0; kk < 16; ++kk) {
        e[kk] = bf16r(expf(av[kk] - m));
        s += e[kk];
    }
#pragma unroll
    for (int kk = 0; kk < 16; ++kk) e[kk] = bf16r(e[kk] / s);
    float rr = 0.f;
#pragma unroll
    for (int kk = 0; kk < 16; ++kk) {
        float vp = bf16r(vf[kk] + posr[kk]);
        rr = fmaf(e[kk], vp, rr);
    }
    res[(size_t)bn * 256 + c] = bf16r(rr);
}

// ---------------------------------------------------------------------------
extern "C" void kernel_launch(void* const* d_in, const int* in_sizes, int n_in,
                              void* d_out, int out_size, void* d_ws, size_t ws_size,
                              hipStream_t stream)
{
    const float* xyz1     = (const float*)d_in[0];
    const float* points1  = (const float*)d_in[1];
    const float* xyz2     = (const float*)d_in[2];
    const float* points2  = (const float*)d_in[3];
    const float* up_w1    = (const float*)d_in[4];
    const float* up_b1    = (const float*)d_in[5];
    const float* up_w2    = (const float*)d_in[6];
    const float* up_b2    = (const float*)d_in[7];
    const float* fc1_w    = (const float*)d_in[8];
    const float* fc1_b    = (const float*)d_in[9];
    const float* fc2_w    = (const float*)d_in[10];
    const float* fc2_b    = (const float*)d_in[11];
    const float* delta_w1 = (const float*)d_in[12];
    const float* delta_b1 = (const float*)d_in[13];
    const float* delta_w2 = (const float*)d_in[14];
    const float* delta_b2 = (const float*)d_in[15];
    const float* gamma_w1 = (const float*)d_in[16];
    const float* gamma_b1 = (const float*)d_in[17];
    const float* gamma_w2 = (const float*)d_in[18];
    const float* gamma_b2 = (const float*)d_in[19];
    const float* wq       = (const float*)d_in[20];
    const float* wk       = (const float*)d_in[21];
    const float* wv       = (const float*)d_in[22];

    float* ws = (float*)d_ws;
    float* f1    = ws;
    float* feats = f1 + (size_t)BB * N1 * 256;
    float* x     = feats + (size_t)BB * N2 * 256;
    float* qb    = x + (size_t)BB * N2 * 256;
    float* kb    = qb + (size_t)BB * N2 * 256;
    float* vb    = kb + (size_t)BB * N2 * 256;
    int*   knn   = (int*)(vb + (size_t)BB * N2 * 256);
    unsigned short* Bd2  = (unsigned short*)(knn + (size_t)BB * N2 * 16);
    unsigned short* Bg1  = Bd2 + 65536;
    unsigned short* Bg2  = Bg1 + 65536;
    unsigned short* Bup1 = Bg2 + 65536;       // 512x256 -> 131072
    unsigned short* Bup2 = Bup1 + 131072;
    unsigned short* Bfc1 = Bup2 + 65536;
    unsigned short* Bfc2 = Bfc1 + 65536;
    unsigned short* Bq   = Bfc2 + 65536;
    unsigned short* Bk   = Bq + 65536;
    unsigned short* Bv   = Bk + 65536;
    float* resb = x;   // x dead after q/k/v

    float* out = (float*)d_out;
    hipMemcpyAsync(out, xyz2, (size_t)BB * N2 * 3 * sizeof(float),
                   hipMemcpyDeviceToDevice, stream);

    const float BN = (float)(1.0 / sqrt(1.0 + 1e-5));

    // all weight swizzles in one launch
    SwzArgs sa;
    sa.W[0] = up_w1;    sa.B[0] = Bup1; sa.K[0] = CIN;
    sa.W[1] = up_w2;    sa.B[1] = Bup2; sa.K[1] = CC;
    sa.W[2] = fc1_w;    sa.B[2] = Bfc1; sa.K[2] = CC;
    sa.W[3] = fc2_w;    sa.B[3] = Bfc2; sa.K[3] = CC;
    sa.W[4] = wq;       sa.B[4] = Bq;   sa.K[4] = CC;
    sa.W[5] = wk;       sa.B[5] = Bk;   sa.K[5] = CC;
    sa.W[6] = wv;       sa.B[6] = Bv;   sa.K[6] = CC;
    sa.W[7] = delta_w2; sa.B[7] = Bd2;  sa.K[7] = CC;
    sa.W[8] = gamma_w1; sa.B[8] = Bg1;  sa.K[8] = CC;
    sa.W[9] = gamma_w2; sa.B[9] = Bg2;  sa.K[9] = CC;
    swizzle_all<<<dim3(64, 10), 256, 0, stream>>>(sa);

    // f2 = relu(bf16(points2) @ bf16(up_w2) * bn) -> feats   [512 blocks]
    gemm_mfma<CC, 8, true, true, false><<<BB * N2 / 64 * 2, 256, 0, stream>>>(
        points2, Bup2, up_b2, nullptr, BN, feats);
    // f1 = relu(bf16(points1) @ bf16(up_w1) * bn)            [256 blocks]
    gemm_mfma<CIN, 4, true, true, false><<<BB * N1 / 64 * 4, 256, 0, stream>>>(
        points1, Bup1, up_b1, nullptr, BN, f1);
    // 3-NN selection (raw fp32 coords) + fused interp add    [256 blocks]
    nn3_interp_kernel<<<BB * 64, 256, 0, stream>>>(xyz1, xyz2, f1, feats);
    // x = bf16r(feats @ bf16(fc1_w))                         [512 blocks]
    gemm_mfma<CC, 8, false, false, false><<<BB * N2 / 64 * 2, 256, 0, stream>>>(
        feats, Bfc1, fc1_b, nullptr, 1.f, x);
    // fused q/k/v                                            [512 blocks]
    qkv_mfma<<<BB * N2 / 64 * 2, 256, 0, stream>>>(x, Bq, Bk, Bv, qb, kb, vb);
    knn_kernel<<<BB * 64, 256, 0, stream>>>(xyz2, knn);
    // MFMA attention, 1 point/block                          [16384 blocks]
    attn_mfma<<<BB * N2, 256, 0, stream>>>(xyz2, qb, kb, vb, knn,
                                           delta_w1, delta_b1, delta_b2, gamma_b1, gamma_b2,
                                           Bd2, Bg1, Bg2, resb);
    // out1 = bf16r(bf16r(resb @ bf16(fc2_w)) + feats)        [512 blocks]
    gemm_mfma<CC, 8, false, false, true><<<BB * N2 / 64 * 2, 256, 0, stream>>>(
        resb, Bfc2, fc2_b, feats, 1.f, out + (size_t)BB * N2 * 3);
}

// Round 17
// 637.369 us; speedup vs baseline: 1.3411x; 1.0897x over previous
//
#include <hip/hip_runtime.h>
#include <hip/hip_bf16.h>
#include <math.h>
#include <float.h>

#define BB   4
#define N1   1024
#define N2   4096
#define CIN  512
#define CC   256
#define DM   256
#define KNNK 16
#define PPB  2

typedef __attribute__((ext_vector_type(8))) short bf16x8;
typedef __attribute__((ext_vector_type(4))) float f32x4;

__device__ __forceinline__ float bf16r(float x) {
    return __bfloat162float(__float2bfloat16(x));
}
__device__ __forceinline__ unsigned short f2bu(float x) {
    __hip_bfloat16 h = __float2bfloat16(x);
    return *reinterpret_cast<unsigned short*>(&h);
}
__device__ __forceinline__ float bu2f(unsigned short u) {
    __hip_bfloat16 h = *reinterpret_cast<__hip_bfloat16*>(&u);
    return __bfloat162float(h);
}

// ---------------------------------------------------------------------------
// All 10 weight swizzles in one launch.
// ---------------------------------------------------------------------------
struct SwzArgs {
    const float* W[10];
    unsigned short* B[10];
    int K[10];
};
__global__ __launch_bounds__(256) void swizzle_all(SwzArgs a)
{
    int m = blockIdx.y;
    int idx = blockIdx.x * 256 + threadIdx.x;
    int total = (a.K[m] >> 5) << 10;
    if (idx >= total) return;
    const float* W = a.W[m];
    unsigned short* B = a.B[m];
    int l = idx & 63;
    int tile = (idx >> 6) & 15;
    int kb = idx >> 10;
    int col = tile * 16 + (l & 15);
    int k0 = kb * 32 + ((l >> 4) << 3);
#pragma unroll
    for (int i = 0; i < 8; ++i)
        B[(size_t)idx * 8 + i] = f2bu(W[(size_t)(k0 + i) * 256 + col]);
}

// ---------------------------------------------------------------------------
// MFMA GEMM, N-split (unchanged — bit-identical)
// ---------------------------------------------------------------------------
template<int KD, int NT, bool RELU, bool BN_, bool RESID>
__global__ __launch_bounds__(256) void gemm_mfma(
    const float* __restrict__ X, const unsigned short* __restrict__ Bw,
    const float* __restrict__ bias, const float* __restrict__ resid,
    float scale, float* __restrict__ Y)
{
    const int NSPLIT = 16 / NT;
    const int c = threadIdx.x;
    const int l = c & 63, wv_ = c >> 6;
    const int lr = l & 15, lg = l >> 4;
    const int row0 = (blockIdx.x / NSPLIT) * 64;
    const int tb = (blockIdx.x % NSPLIT) * NT;
    __shared__ __align__(16) unsigned short As[64][72];

    f32x4 acc[NT];
#pragma unroll
    for (int t = 0; t < NT; ++t) acc[t] = (f32x4){0.f, 0.f, 0.f, 0.f};

    const int rs = c >> 2, c0 = (c & 3) * 16;
    for (int ks = 0; ks < KD / 64; ++ks) {
        const float* src = X + (size_t)(row0 + rs) * KD + ks * 64 + c0;
#pragma unroll
        for (int i = 0; i < 16; i += 4) {
            float4 v = *(const float4*)(src + i);
            As[rs][c0 + i + 0] = f2bu(v.x);
            As[rs][c0 + i + 1] = f2bu(v.y);
            As[rs][c0 + i + 2] = f2bu(v.z);
            As[rs][c0 + i + 3] = f2bu(v.w);
        }
        __syncthreads();
#pragma unroll
        for (int kbl = 0; kbl < 2; ++kbl) {
            int kb = ks * 2 + kbl;
            bf16x8 af = *(const bf16x8*)&As[wv_ * 16 + lr][kbl * 32 + lg * 8];
#pragma unroll
            for (int t = 0; t < NT; ++t) {
                bf16x8 bf = *(const bf16x8*)&Bw[((size_t)(kb * 16 + tb + t) * 64 + l) * 8];
                acc[t] = __builtin_amdgcn_mfma_f32_16x16x32_bf16(af, bf, acc[t], 0, 0, 0);
            }
        }
        __syncthreads();
    }
#pragma unroll
    for (int t = 0; t < NT; ++t) {
        int col = (tb + t) * 16 + lr;
        float bb = bias ? bias[col] : 0.f;
#pragma unroll
        for (int r = 0; r < 4; ++r) {
            size_t row = row0 + wv_ * 16 + lg * 4 + r;
            float v = bf16r(acc[t][r]);
            v = bf16r(v + bb);
            if (BN_) v = bf16r(v * scale);
            if (RELU) v = fmaxf(v, 0.f);
            if (RESID) v = bf16r(v + resid[row * 256 + col]);
            Y[row * 256 + col] = v;
        }
    }
}

// ---------------------------------------------------------------------------
// Fused q/k/v GEMM (unchanged — bit-identical)
// ---------------------------------------------------------------------------
__global__ __launch_bounds__(256) void qkv_mfma(
    const float* __restrict__ X,
    const unsigned short* __restrict__ Bq,
    const unsigned short* __restrict__ Bk,
    const unsigned short* __restrict__ Bv,
    float* __restrict__ Yq, float* __restrict__ Yk, float* __restrict__ Yv)
{
    const int NT = 8;
    const int c = threadIdx.x;
    const int l = c & 63, wv_ = c >> 6;
    const int lr = l & 15, lg = l >> 4;
    const int row0 = (blockIdx.x >> 1) * 64;
    const int tb = (blockIdx.x & 1) * NT;
    __shared__ __align__(16) unsigned short As[64][72];

    f32x4 aq[NT], ak[NT], av_[NT];
#pragma unroll
    for (int t = 0; t < NT; ++t) {
        aq[t] = (f32x4){0.f, 0.f, 0.f, 0.f};
        ak[t] = aq[t]; av_[t] = aq[t];
    }

    const int rs = c >> 2, c0 = (c & 3) * 16;
    for (int ks = 0; ks < CC / 64; ++ks) {
        const float* src = X + (size_t)(row0 + rs) * CC + ks * 64 + c0;
#pragma unroll
        for (int i = 0; i < 16; i += 4) {
            float4 v = *(const float4*)(src + i);
            As[rs][c0 + i + 0] = f2bu(v.x);
            As[rs][c0 + i + 1] = f2bu(v.y);
            As[rs][c0 + i + 2] = f2bu(v.z);
            As[rs][c0 + i + 3] = f2bu(v.w);
        }
        __syncthreads();
#pragma unroll
        for (int kbl = 0; kbl < 2; ++kbl) {
            int kb = ks * 2 + kbl;
            bf16x8 af = *(const bf16x8*)&As[wv_ * 16 + lr][kbl * 32 + lg * 8];
#pragma unroll
            for (int t = 0; t < NT; ++t) {
                size_t fo = ((size_t)(kb * 16 + tb + t) * 64 + l) * 8;
                bf16x8 bq = *(const bf16x8*)&Bq[fo];
                bf16x8 bk = *(const bf16x8*)&Bk[fo];
                bf16x8 bv = *(const bf16x8*)&Bv[fo];
                aq[t]  = __builtin_amdgcn_mfma_f32_16x16x32_bf16(af, bq, aq[t], 0, 0, 0);
                ak[t]  = __builtin_amdgcn_mfma_f32_16x16x32_bf16(af, bk, ak[t], 0, 0, 0);
                av_[t] = __builtin_amdgcn_mfma_f32_16x16x32_bf16(af, bv, av_[t], 0, 0, 0);
            }
        }
        __syncthreads();
    }
#pragma unroll
    for (int t = 0; t < NT; ++t) {
        int col = (tb + t) * 16 + lr;
#pragma unroll
        for (int r = 0; r < 4; ++r) {
            size_t row = row0 + wv_ * 16 + lg * 4 + r;
            Yq[row * 256 + col] = bf16r(aq[t][r]);
            Yk[row * 256 + col] = bf16r(ak[t][r]);
            Yv[row * 256 + col] = bf16r(av_[t][r]);
        }
    }
}

// ---- faithful fp32 distance (selection on RAW fp32 coords) ---------------
__device__ __forceinline__ float norm2_ref(float x, float y, float z) {
    return __fadd_rn(__fadd_rn(__fmul_rn(x, x), __fmul_rn(y, y)), __fmul_rn(z, z));
}
__device__ __forceinline__ float dist_ref(float sa, float nb,
                                          float ax, float ay, float az,
                                          float bx, float by, float bz) {
    float dot = __fadd_rn(__fadd_rn(__fmul_rn(ax, bx), __fmul_rn(ay, by)),
                          __fmul_rn(az, bz));
    return __fsub_rn(__fadd_rn(sa, nb), __fmul_rn(2.f, dot));
}

// ---------------------------------------------------------------------------
// 3-NN + fused interpolation (unchanged — bit-identical selection)
// ---------------------------------------------------------------------------
__global__ __launch_bounds__(256) void nn3_interp_kernel(
    const float* __restrict__ xyz1, const float* __restrict__ xyz2,
    const float* __restrict__ f1, float* __restrict__ feats)
{
    const int b = blockIdx.x >> 6;
    const int q0 = (blockIdx.x & 63) << 6;
    const int tid = threadIdx.x;
    const int ql = tid >> 2, r = tid & 3;
    const int n = q0 + ql;
    __shared__ float sx[N1], sy[N1], sz[N1], snb[N1];
    __shared__ float sd[64][4][3];
    __shared__ int   si[64][4][3];
    __shared__ float sw[64][3];
    __shared__ int   sidx[64][3];
    for (int i = tid; i < N1; i += 256) {
        const float* p = xyz1 + ((size_t)b * N1 + i) * 3;
        float x = p[0], y = p[1], z = p[2];
        sx[i] = x; sy[i] = y; sz[i] = z;
        snb[i] = norm2_ref(x, y, z);
    }
    __syncthreads();
    const float* pq = xyz2 + ((size_t)b * N2 + n) * 3;
    const float ax = pq[0], ay = pq[1], az = pq[2];
    const float sa = norm2_ref(ax, ay, az);
    float d0 = FLT_MAX, d1 = FLT_MAX, d2 = FLT_MAX;
    int i0 = 0, i1 = 0, i2 = 0;
    const int jb = r << 8;
    for (int jj = 0; jj < 256; ++jj) {
        int j = jb + jj;
        float dist = dist_ref(sa, snb[j], ax, ay, az, sx[j], sy[j], sz[j]);
        if (dist < d2) {
            if (dist < d1) {
                d2 = d1; i2 = i1;
                if (dist < d0) { d1 = d0; i1 = i0; d0 = dist; i0 = j; }
                else           { d1 = dist; i1 = j; }
            } else { d2 = dist; i2 = j; }
        }
    }
    sd[ql][r][0] = d0; sd[ql][r][1] = d1; sd[ql][r][2] = d2;
    si[ql][r][0] = i0; si[ql][r][1] = i1; si[ql][r][2] = i2;
    __syncthreads();
    if (r == 0) {
        int p0 = 0, p1 = 0, p2 = 0, p3 = 0;
        float md[3]; int mi[3];
        for (int o = 0; o < 3; ++o) {
            float h0 = (p0 < 3) ? sd[ql][0][p0] : FLT_MAX;
            float h1 = (p1 < 3) ? sd[ql][1][p1] : FLT_MAX;
            float h2 = (p2 < 3) ? sd[ql][2][p2] : FLT_MAX;
            float h3 = (p3 < 3) ? sd[ql][3][p3] : FLT_MAX;
            int br = 0; float bd = h0;
            if (h1 < bd) { bd = h1; br = 1; }
            if (h2 < bd) { bd = h2; br = 2; }
            if (h3 < bd) { bd = h3; br = 3; }
            if (br == 0)      { mi[o] = si[ql][0][p0]; md[o] = h0; ++p0; }
            else if (br == 1) { mi[o] = si[ql][1][p1]; md[o] = h1; ++p1; }
            else if (br == 2) { mi[o] = si[ql][2][p2]; md[o] = h2; ++p2; }
            else              { mi[o] = si[ql][3][p3]; md[o] = h3; ++p3; }
        }
        float r0 = __fdiv_rn(1.f, __fadd_rn(md[0], 1e-8f));
        float r1 = __fdiv_rn(1.f, __fadd_rn(md[1], 1e-8f));
        float r2 = __fdiv_rn(1.f, __fadd_rn(md[2], 1e-8f));
        float s  = __fadd_rn(__fadd_rn(r0, r1), r2);
        sw[ql][0] = __fdiv_rn(r0, s);
        sw[ql][1] = __fdiv_rn(r1, s);
        sw[ql][2] = __fdiv_rn(r2, s);
        sidx[ql][0] = mi[0]; sidx[ql][1] = mi[1]; sidx[ql][2] = mi[2];
    }
    __syncthreads();
    const float* f1b = f1 + (size_t)b * N1 * 256;
    for (int p = 0; p < 64; ++p) {
        int bn = (b << 12) + q0 + p;
        float w0 = sw[p][0], w1 = sw[p][1], w2 = sw[p][2];
        int j0 = sidx[p][0], j1 = sidx[p][1], j2 = sidx[p][2];
        float itp = w0 * f1b[(size_t)j0 * 256 + tid]
                  + w1 * f1b[(size_t)j1 * 256 + tid]
                  + w2 * f1b[(size_t)j2 * 256 + tid];
        feats[(size_t)bn * 256 + tid] = bf16r(bf16r(itp) + feats[(size_t)bn * 256 + tid]);
    }
}

// ---------------------------------------------------------------------------
// KNN top-16 (unchanged — bit-identical selection)
// ---------------------------------------------------------------------------
__global__ __launch_bounds__(256) void knn_kernel(
    const float* __restrict__ xyz2, int* __restrict__ knn_out)
{
    const int b = blockIdx.x >> 6;
    const int q0 = (blockIdx.x & 63) << 6;
    const int tid = threadIdx.x;
    const int ql = tid >> 2, r = tid & 3;
    const int n = q0 + ql;
    __shared__ float sx[N2], sy[N2], sz[N2], sn[N2];
    __shared__ float sd[64][4][16];
    __shared__ int   si[64][4][16];
    for (int i = tid; i < N2; i += 256) {
        const float* p = xyz2 + ((size_t)b * N2 + i) * 3;
        float x = p[0], y = p[1], z = p[2];
        sx[i] = x; sy[i] = y; sz[i] = z;
        sn[i] = norm2_ref(x, y, z);
    }
    __syncthreads();
    const float ax = sx[n], ay = sy[n], az = sz[n];
    const float sa = sn[n];
    float d[16]; int id[16];
#pragma unroll
    for (int s = 0; s < 16; ++s) { d[s] = FLT_MAX; id[s] = 0; }
    const int jbase = r << 10;
    for (int jj = 0; jj < 1024; ++jj) {
        int j = jbase + jj;
        float dist = dist_ref(sa, sn[j], ax, ay, az, sx[j], sy[j], sz[j]);
        if (dist < d[15]) {
#pragma unroll
            for (int s = 15; s >= 0; --s) {
                bool shift = (s > 0) && (dist < d[s - 1]);
                bool place = (dist < d[s]) && !shift;
                float nd = shift ? d[s - 1] : (place ? dist : d[s]);
                int   ni = shift ? id[s - 1] : (place ? j : id[s]);
                d[s] = nd; id[s] = ni;
            }
        }
    }
#pragma unroll
    for (int s = 0; s < 16; ++s) { sd[ql][r][s] = d[s]; si[ql][r][s] = id[s]; }
    __syncthreads();
    if (r == 0) {
        int p0 = 0, p1 = 0, p2 = 0, p3 = 0;
        size_t ob = ((size_t)b * N2 + n) * 16;
        for (int o = 0; o < 16; ++o) {
            float h0 = (p0 < 16) ? sd[ql][0][p0] : FLT_MAX;
            float h1 = (p1 < 16) ? sd[ql][1][p1] : FLT_MAX;
            float h2 = (p2 < 16) ? sd[ql][2][p2] : FLT_MAX;
            float h3 = (p3 < 16) ? sd[ql][3][p3] : FLT_MAX;
            int br = 0; float bd = h0;
            if (h1 < bd) { bd = h1; br = 1; }
            if (h2 < bd) { bd = h2; br = 2; }
            if (h3 < bd) { bd = h3; br = 3; }
            int bi;
            if (br == 0)      { bi = si[ql][0][p0]; ++p0; }
            else if (br == 1) { bi = si[ql][1][p1]; ++p1; }
            else if (br == 2) { bi = si[ql][2][p2]; ++p2; }
            else              { bi = si[ql][3][p3]; ++p3; }
            knn_out[ob + o] = bi;
        }
    }
}

// ---------------------------------------------------------------------------
// MFMA attention, 2 points per block. Per-point arithmetic bit-identical to
// round 16 (same chains, same rounding points). LDS 34.8 KB -> 4 blocks/CU;
// B-fragments loaded once per kb, reused across both points.
// kf preloaded (latency hidden over ph/pos); vf loaded inline at the end.
// ---------------------------------------------------------------------------
__global__ __launch_bounds__(256) void attn_mfma2(
    const float* __restrict__ xyz2, const float* __restrict__ qg,
    const float* __restrict__ kg, const float* __restrict__ vg,
    const int* __restrict__ knn,
    const float* __restrict__ d1w, const float* __restrict__ d1b,
    const float* __restrict__ d2b, const float* __restrict__ g1b,
    const float* __restrict__ g2b,
    const unsigned short* __restrict__ Bd2,
    const unsigned short* __restrict__ Bg1,
    const unsigned short* __restrict__ Bg2,
    float* __restrict__ res)
{
    const int bn0 = blockIdx.x * PPB;
    const int b = bn0 >> 12;
    const int c = threadIdx.x;
    const int l = c & 63, wv_ = c >> 6;
    const int lr = l & 15, lg = l >> 4;

    __shared__ __align__(16) unsigned short phb[PPB * 16][264];
    __shared__ __align__(16) unsigned short posb[PPB * 16][264];
    __shared__ int   knn_s[PPB][16];
    __shared__ float relx[PPB][16], rely[PPB][16], relz[PPB][16];

    if (c < PPB * 16) {
        int p = c >> 4, kk = c & 15;
        int idx = knn[(size_t)(bn0 + p) * 16 + kk];
        knn_s[p][kk] = idx;
        const float* pq = xyz2 + (size_t)(bn0 + p) * 3;
        const float* pk = xyz2 + ((size_t)b * N2 + idx) * 3;
        relx[p][kk] = bf16r(pq[0] - pk[0]);
        rely[p][kk] = bf16r(pq[1] - pk[1]);
        relz[p][kk] = bf16r(pq[2] - pk[2]);
    }
    __syncthreads();

    const size_t basebc = (size_t)b * N2 * 256;
    float kf[PPB][16], qv[PPB];
#pragma unroll
    for (int p = 0; p < PPB; ++p) {
        qv[p] = qg[(size_t)(bn0 + p) * 256 + c];
#pragma unroll
        for (int kk = 0; kk < 16; ++kk)
            kf[p][kk] = kg[basebc + (size_t)knn_s[p][kk] * 256 + c];
    }

    // ph = relu(bf16r(rel @ d1w + d1b))
    {
        float w0 = bf16r(d1w[c]), w1 = bf16r(d1w[256 + c]), w2 = bf16r(d1w[512 + c]);
        float bb = d1b[c];
#pragma unroll
        for (int p = 0; p < PPB; ++p)
#pragma unroll
            for (int kk = 0; kk < 16; ++kk) {
                float v = fmaf(relx[p][kk], w0, fmaf(rely[p][kk], w1, fmaf(relz[p][kk], w2, bb)));
                phb[p * 16 + kk][c] = f2bu(fmaxf(v, 0.f));
            }
    }
    __syncthreads();

    f32x4 acc[PPB][4];
    // ---- pos chain ----
#pragma unroll
    for (int p = 0; p < PPB; ++p)
#pragma unroll
        for (int t = 0; t < 4; ++t) acc[p][t] = (f32x4){0.f, 0.f, 0.f, 0.f};
    for (int kb = 0; kb < 8; ++kb) {
        bf16x8 bfr[4];
#pragma unroll
        for (int t = 0; t < 4; ++t)
            bfr[t] = *(const bf16x8*)&Bd2[((size_t)(kb * 16 + wv_ * 4 + t) * 64 + l) * 8];
#pragma unroll
        for (int p = 0; p < PPB; ++p) {
            bf16x8 af = *(const bf16x8*)&phb[p * 16 + lr][kb * 32 + lg * 8];
#pragma unroll
            for (int t = 0; t < 4; ++t)
                acc[p][t] = __builtin_amdgcn_mfma_f32_16x16x32_bf16(af, bfr[t], acc[p][t], 0, 0, 0);
        }
    }
#pragma unroll
    for (int p = 0; p < PPB; ++p)
#pragma unroll
        for (int t = 0; t < 4; ++t) {
            int col = (wv_ * 4 + t) * 16 + lr;
            float bb = d2b[col];
#pragma unroll
            for (int r = 0; r < 4; ++r)
                posb[p * 16 + lg * 4 + r][col] = f2bu(acc[p][t][r] + bb);
        }
    __syncthreads();

    // t = bf16r(bf16r(q - kf) + pos)
    float posr[PPB][16];
#pragma unroll
    for (int p = 0; p < PPB; ++p)
#pragma unroll
        for (int kk = 0; kk < 16; ++kk) posr[p][kk] = bu2f(posb[p * 16 + kk][c]);
#pragma unroll
    for (int p = 0; p < PPB; ++p)
#pragma unroll
        for (int kk = 0; kk < 16; ++kk)
            phb[p * 16 + kk][c] = f2bu(bf16r(qv[p] - kf[p][kk]) + posr[p][kk]);
    __syncthreads();

    // ---- h chain ----
#pragma unroll
    for (int p = 0; p < PPB; ++p)
#pragma unroll
        for (int t = 0; t < 4; ++t) acc[p][t] = (f32x4){0.f, 0.f, 0.f, 0.f};
    for (int kb = 0; kb < 8; ++kb) {
        bf16x8 bfr[4];
#pragma unroll
        for (int t = 0; t < 4; ++t)
            bfr[t] = *(const bf16x8*)&Bg1[((size_t)(kb * 16 + wv_ * 4 + t) * 64 + l) * 8];
#pragma unroll
        for (int p = 0; p < PPB; ++p) {
            bf16x8 af = *(const bf16x8*)&phb[p * 16 + lr][kb * 32 + lg * 8];
#pragma unroll
            for (int t = 0; t < 4; ++t)
                acc[p][t] = __builtin_amdgcn_mfma_f32_16x16x32_bf16(af, bfr[t], acc[p][t], 0, 0, 0);
        }
    }
    __syncthreads();
#pragma unroll
    for (int p = 0; p < PPB; ++p)
#pragma unroll
        for (int t = 0; t < 4; ++t) {
            int col = (wv_ * 4 + t) * 16 + lr;
            float bb = g1b[col];
#pragma unroll
            for (int r = 0; r < 4; ++r)
                phb[p * 16 + lg * 4 + r][col] = f2bu(fmaxf(acc[p][t][r] + bb, 0.f));
        }
    __syncthreads();

    // ---- a chain ----
#pragma unroll
    for (int p = 0; p < PPB; ++p)
#pragma unroll
        for (int t = 0; t < 4; ++t) acc[p][t] = (f32x4){0.f, 0.f, 0.f, 0.f};
    for (int kb = 0; kb < 8; ++kb) {
        bf16x8 bfr[4];
#pragma unroll
        for (int t = 0; t < 4; ++t)
            bfr[t] = *(const bf16x8*)&Bg2[((size_t)(kb * 16 + wv_ * 4 + t) * 64 + l) * 8];
#pragma unroll
        for (int p = 0; p < PPB; ++p) {
            bf16x8 af = *(const bf16x8*)&phb[p * 16 + lr][kb * 32 + lg * 8];
#pragma unroll
            for (int t = 0; t < 4; ++t)
                acc[p][t] = __builtin_amdgcn_mfma_f32_16x16x32_bf16(af, bfr[t], acc[p][t], 0, 0, 0);
        }
    }
#pragma unroll
    for (int p = 0; p < PPB; ++p)
#pragma unroll
        for (int t = 0; t < 4; ++t) {
            int col = (wv_ * 4 + t) * 16 + lr;
            float bb = g2b[col];
#pragma unroll
            for (int r = 0; r < 4; ++r)
                posb[p * 16 + lg * 4 + r][col] = f2bu(acc[p][t][r] + bb);
        }
    __syncthreads();

    // softmax + weighted sum per point (identical per-thread chain)
#pragma unroll
    for (int p = 0; p < PPB; ++p) {
        float av[16];
#pragma unroll
        for (int kk = 0; kk < 16; ++kk) av[kk] = bu2f(posb[p * 16 + kk][c]) * 0.0625f;
        float m = av[0];
#pragma unroll
        for (int kk = 1; kk < 16; ++kk) m = fmaxf(m, av[kk]);
        float e[16];
        float s = 0.f;
#pragma unroll
        for (int kk = 0; kk < 16; ++kk) {
            e[kk] = bf16r(expf(av[kk] - m));
            s += e[kk];
        }
#pragma unroll
        for (int kk = 0; kk < 16; ++kk) e[kk] = bf16r(e[kk] / s);
        float rr = 0.f;
#pragma unroll
        for (int kk = 0; kk < 16; ++kk) {
            float vfv = vg[basebc + (size_t)knn_s[p][kk] * 256 + c];
            float vp = bf16r(vfv + posr[p][kk]);
            rr = fmaf(e[kk], vp, rr);
        }
        res[(size_t)(bn0 + p) * 256 + c] = bf16r(rr);
    }
}

// ---------------------------------------------------------------------------
extern "C" void kernel_launch(void* const* d_in, const int* in_sizes, int n_in,
                              void* d_out, int out_size, void* d_ws, size_t ws_size,
                              hipStream_t stream)
{
    const float* xyz1     = (const float*)d_in[0];
    const float* points1  = (const float*)d_in[1];
    const float* xyz2     = (const float*)d_in[2];
    const float* points2  = (const float*)d_in[3];
    const float* up_w1    = (const float*)d_in[4];
    const float* up_b1    = (const float*)d_in[5];
    const float* up_w2    = (const float*)d_in[6];
    const float* up_b2    = (const float*)d_in[7];
    const float* fc1_w    = (const float*)d_in[8];
    const float* fc1_b    = (const float*)d_in[9];
    const float* fc2_w    = (const float*)d_in[10];
    const float* fc2_b    = (const float*)d_in[11];
    const float* delta_w1 = (const float*)d_in[12];
    const float* delta_b1 = (const float*)d_in[13];
    const float* delta_w2 = (const float*)d_in[14];
    const float* delta_b2 = (const float*)d_in[15];
    const float* gamma_w1 = (const float*)d_in[16];
    const float* gamma_b1 = (const float*)d_in[17];
    const float* gamma_w2 = (const float*)d_in[18];
    const float* gamma_b2 = (const float*)d_in[19];
    const float* wq       = (const float*)d_in[20];
    const float* wk       = (const float*)d_in[21];
    const float* wv       = (const float*)d_in[22];

    float* ws = (float*)d_ws;
    float* f1    = ws;
    float* feats = f1 + (size_t)BB * N1 * 256;
    float* x     = feats + (size_t)BB * N2 * 256;
    float* qb    = x + (size_t)BB * N2 * 256;
    float* kb    = qb + (size_t)BB * N2 * 256;
    float* vb    = kb + (size_t)BB * N2 * 256;
    int*   knn   = (int*)(vb + (size_t)BB * N2 * 256);
    unsigned short* Bd2  = (unsigned short*)(knn + (size_t)BB * N2 * 16);
    unsigned short* Bg1  = Bd2 + 65536;
    unsigned short* Bg2  = Bg1 + 65536;
    unsigned short* Bup1 = Bg2 + 65536;
    unsigned short* Bup2 = Bup1 + 131072;
    unsigned short* Bfc1 = Bup2 + 65536;
    unsigned short* Bfc2 = Bfc1 + 65536;
    unsigned short* Bq   = Bfc2 + 65536;
    unsigned short* Bk   = Bq + 65536;
    unsigned short* Bv   = Bk + 65536;
    float* resb = x;   // x dead after q/k/v

    float* out = (float*)d_out;
    hipMemcpyAsync(out, xyz2, (size_t)BB * N2 * 3 * sizeof(float),
                   hipMemcpyDeviceToDevice, stream);

    const float BN = (float)(1.0 / sqrt(1.0 + 1e-5));

    SwzArgs sa;
    sa.W[0] = up_w1;    sa.B[0] = Bup1; sa.K[0] = CIN;
    sa.W[1] = up_w2;    sa.B[1] = Bup2; sa.K[1] = CC;
    sa.W[2] = fc1_w;    sa.B[2] = Bfc1; sa.K[2] = CC;
    sa.W[3] = fc2_w;    sa.B[3] = Bfc2; sa.K[3] = CC;
    sa.W[4] = wq;       sa.B[4] = Bq;   sa.K[4] = CC;
    sa.W[5] = wk;       sa.B[5] = Bk;   sa.K[5] = CC;
    sa.W[6] = wv;       sa.B[6] = Bv;   sa.K[6] = CC;
    sa.W[7] = delta_w2; sa.B[7] = Bd2;  sa.K[7] = CC;
    sa.W[8] = gamma_w1; sa.B[8] = Bg1;  sa.K[8] = CC;
    sa.W[9] = gamma_w2; sa.B[9] = Bg2;  sa.K[9] = CC;
    swizzle_all<<<dim3(64, 10), 256, 0, stream>>>(sa);

    gemm_mfma<CC, 8, true, true, false><<<BB * N2 / 64 * 2, 256, 0, stream>>>(
        points2, Bup2, up_b2, nullptr, BN, feats);
    gemm_mfma<CIN, 4, true, true, false><<<BB * N1 / 64 * 4, 256, 0, stream>>>(
        points1, Bup1, up_b1, nullptr, BN, f1);
    nn3_interp_kernel<<<BB * 64, 256, 0, stream>>>(xyz1, xyz2, f1, feats);
    gemm_mfma<CC, 8, false, false, false><<<BB * N2 / 64 * 2, 256, 0, stream>>>(
        feats, Bfc1, fc1_b, nullptr, 1.f, x);
    qkv_mfma<<<BB * N2 / 64 * 2, 256, 0, stream>>>(x, Bq, Bk, Bv, qb, kb, vb);
    knn_kernel<<<BB * 64, 256, 0, stream>>>(xyz2, knn);
    // MFMA attention, 2 points/block                         [8192 blocks]
    attn_mfma2<<<BB * N2 / PPB, 256, 0, stream>>>(xyz2, qb, kb, vb, knn,
                                                  delta_w1, delta_b1, delta_b2, gamma_b1, gamma_b2,
                                                  Bd2, Bg1, Bg2, resb);
    gemm_mfma<CC, 8, false, false, true><<<BB * N2 / 64 * 2, 256, 0, stream>>>(
        resb, Bfc2, fc2_b, feats, 1.f, out + (size_t)BB * N2 * 3);
}

// Round 19
// 634.460 us; speedup vs baseline: 1.3472x; 1.0046x over previous
//
#include <hip/hip_runtime.h>
#include <hip/hip_bf16.h>
#include <math.h>
#include <float.h>

#define BB   4
#define N1   1024
#define N2   4096
#define CIN  512
#define CC   256
#define DM   256
#define KNNK 16
#define PPB  2

typedef __attribute__((ext_vector_type(8))) short bf16x8;
typedef __attribute__((ext_vector_type(4))) float f32x4;

__device__ __forceinline__ float bf16r(float x) {
    return __bfloat162float(__float2bfloat16(x));
}
__device__ __forceinline__ unsigned short f2bu(float x) {
    __hip_bfloat16 h = __float2bfloat16(x);
    return *reinterpret_cast<unsigned short*>(&h);
}
__device__ __forceinline__ float bu2f(unsigned short u) {
    __hip_bfloat16 h = *reinterpret_cast<__hip_bfloat16*>(&u);
    return __bfloat162float(h);
}

// ---------------------------------------------------------------------------
// All 10 weight swizzles in one launch.
// ---------------------------------------------------------------------------
struct SwzArgs {
    const float* W[10];
    unsigned short* B[10];
    int K[10];
};
__global__ __launch_bounds__(256) void swizzle_all(SwzArgs a)
{
    int m = blockIdx.y;
    int idx = blockIdx.x * 256 + threadIdx.x;
    int total = (a.K[m] >> 5) << 10;
    if (idx >= total) return;
    const float* W = a.W[m];
    unsigned short* B = a.B[m];
    int l = idx & 63;
    int tile = (idx >> 6) & 15;
    int kb = idx >> 10;
    int col = tile * 16 + (l & 15);
    int k0 = kb * 32 + ((l >> 4) << 3);
#pragma unroll
    for (int i = 0; i < 8; ++i)
        B[(size_t)idx * 8 + i] = f2bu(W[(size_t)(k0 + i) * 256 + col]);
}

// ---------------------------------------------------------------------------
// MFMA GEMM, N-split (unchanged — bit-identical)
// ---------------------------------------------------------------------------
template<int KD, int NT, bool RELU, bool BN_, bool RESID>
__global__ __launch_bounds__(256) void gemm_mfma(
    const float* __restrict__ X, const unsigned short* __restrict__ Bw,
    const float* __restrict__ bias, const float* __restrict__ resid,
    float scale, float* __restrict__ Y)
{
    const int NSPLIT = 16 / NT;
    const int c = threadIdx.x;
    const int l = c & 63, wv_ = c >> 6;
    const int lr = l & 15, lg = l >> 4;
    const int row0 = (blockIdx.x / NSPLIT) * 64;
    const int tb = (blockIdx.x % NSPLIT) * NT;
    __shared__ __align__(16) unsigned short As[64][72];

    f32x4 acc[NT];
#pragma unroll
    for (int t = 0; t < NT; ++t) acc[t] = (f32x4){0.f, 0.f, 0.f, 0.f};

    const int rs = c >> 2, c0 = (c & 3) * 16;
    for (int ks = 0; ks < KD / 64; ++ks) {
        const float* src = X + (size_t)(row0 + rs) * KD + ks * 64 + c0;
#pragma unroll
        for (int i = 0; i < 16; i += 4) {
            float4 v = *(const float4*)(src + i);
            As[rs][c0 + i + 0] = f2bu(v.x);
            As[rs][c0 + i + 1] = f2bu(v.y);
            As[rs][c0 + i + 2] = f2bu(v.z);
            As[rs][c0 + i + 3] = f2bu(v.w);
        }
        __syncthreads();
#pragma unroll
        for (int kbl = 0; kbl < 2; ++kbl) {
            int kb = ks * 2 + kbl;
            bf16x8 af = *(const bf16x8*)&As[wv_ * 16 + lr][kbl * 32 + lg * 8];
#pragma unroll
            for (int t = 0; t < NT; ++t) {
                bf16x8 bf = *(const bf16x8*)&Bw[((size_t)(kb * 16 + tb + t) * 64 + l) * 8];
                acc[t] = __builtin_amdgcn_mfma_f32_16x16x32_bf16(af, bf, acc[t], 0, 0, 0);
            }
        }
        __syncthreads();
    }
#pragma unroll
    for (int t = 0; t < NT; ++t) {
        int col = (tb + t) * 16 + lr;
        float bb = bias ? bias[col] : 0.f;
#pragma unroll
        for (int r = 0; r < 4; ++r) {
            size_t row = row0 + wv_ * 16 + lg * 4 + r;
            float v = bf16r(acc[t][r]);
            v = bf16r(v + bb);
            if (BN_) v = bf16r(v * scale);
            if (RELU) v = fmaxf(v, 0.f);
            if (RESID) v = bf16r(v + resid[row * 256 + col]);
            Y[row * 256 + col] = v;
        }
    }
}

// ---------------------------------------------------------------------------
// Fused q/k/v GEMM (unchanged — bit-identical)
// ---------------------------------------------------------------------------
__global__ __launch_bounds__(256) void qkv_mfma(
    const float* __restrict__ X,
    const unsigned short* __restrict__ Bq,
    const unsigned short* __restrict__ Bk,
    const unsigned short* __restrict__ Bv,
    float* __restrict__ Yq, float* __restrict__ Yk, float* __restrict__ Yv)
{
    const int NT = 8;
    const int c = threadIdx.x;
    const int l = c & 63, wv_ = c >> 6;
    const int lr = l & 15, lg = l >> 4;
    const int row0 = (blockIdx.x >> 1) * 64;
    const int tb = (blockIdx.x & 1) * NT;
    __shared__ __align__(16) unsigned short As[64][72];

    f32x4 aq[NT], ak[NT], av_[NT];
#pragma unroll
    for (int t = 0; t < NT; ++t) {
        aq[t] = (f32x4){0.f, 0.f, 0.f, 0.f};
        ak[t] = aq[t]; av_[t] = aq[t];
    }

    const int rs = c >> 2, c0 = (c & 3) * 16;
    for (int ks = 0; ks < CC / 64; ++ks) {
        const float* src = X + (size_t)(row0 + rs) * CC + ks * 64 + c0;
#pragma unroll
        for (int i = 0; i < 16; i += 4) {
            float4 v = *(const float4*)(src + i);
            As[rs][c0 + i + 0] = f2bu(v.x);
            As[rs][c0 + i + 1] = f2bu(v.y);
            As[rs][c0 + i + 2] = f2bu(v.z);
            As[rs][c0 + i + 3] = f2bu(v.w);
        }
        __syncthreads();
#pragma unroll
        for (int kbl = 0; kbl < 2; ++kbl) {
            int kb = ks * 2 + kbl;
            bf16x8 af = *(const bf16x8*)&As[wv_ * 16 + lr][kbl * 32 + lg * 8];
#pragma unroll
            for (int t = 0; t < NT; ++t) {
                size_t fo = ((size_t)(kb * 16 + tb + t) * 64 + l) * 8;
                bf16x8 bq = *(const bf16x8*)&Bq[fo];
                bf16x8 bk = *(const bf16x8*)&Bk[fo];
                bf16x8 bv = *(const bf16x8*)&Bv[fo];
                aq[t]  = __builtin_amdgcn_mfma_f32_16x16x32_bf16(af, bq, aq[t], 0, 0, 0);
                ak[t]  = __builtin_amdgcn_mfma_f32_16x16x32_bf16(af, bk, ak[t], 0, 0, 0);
                av_[t] = __builtin_amdgcn_mfma_f32_16x16x32_bf16(af, bv, av_[t], 0, 0, 0);
            }
        }
        __syncthreads();
    }
#pragma unroll
    for (int t = 0; t < NT; ++t) {
        int col = (tb + t) * 16 + lr;
#pragma unroll
        for (int r = 0; r < 4; ++r) {
            size_t row = row0 + wv_ * 16 + lg * 4 + r;
            Yq[row * 256 + col] = bf16r(aq[t][r]);
            Yk[row * 256 + col] = bf16r(ak[t][r]);
            Yv[row * 256 + col] = bf16r(av_[t][r]);
        }
    }
}

// ---- faithful fp32 distance (selection on RAW fp32 coords) ---------------
__device__ __forceinline__ float norm2_ref(float x, float y, float z) {
    return __fadd_rn(__fadd_rn(__fmul_rn(x, x), __fmul_rn(y, y)), __fmul_rn(z, z));
}
__device__ __forceinline__ float dist_ref(float sa, float nb,
                                          float ax, float ay, float az,
                                          float bx, float by, float bz) {
    float dot = __fadd_rn(__fadd_rn(__fmul_rn(ax, bx), __fmul_rn(ay, by)),
                          __fmul_rn(az, bz));
    return __fsub_rn(__fadd_rn(sa, nb), __fmul_rn(2.f, dot));
}

// ---------------------------------------------------------------------------
// 3-NN + fused interpolation (unchanged — bit-identical selection)
// ---------------------------------------------------------------------------
__global__ __launch_bounds__(256) void nn3_interp_kernel(
    const float* __restrict__ xyz1, const float* __restrict__ xyz2,
    const float* __restrict__ f1, float* __restrict__ feats)
{
    const int b = blockIdx.x >> 6;
    const int q0 = (blockIdx.x & 63) << 6;
    const int tid = threadIdx.x;
    const int ql = tid >> 2, r = tid & 3;
    const int n = q0 + ql;
    __shared__ float sx[N1], sy[N1], sz[N1], snb[N1];
    __shared__ float sd[64][4][3];
    __shared__ int   si[64][4][3];
    __shared__ float sw[64][3];
    __shared__ int   sidx[64][3];
    for (int i = tid; i < N1; i += 256) {
        const float* p = xyz1 + ((size_t)b * N1 + i) * 3;
        float x = p[0], y = p[1], z = p[2];
        sx[i] = x; sy[i] = y; sz[i] = z;
        snb[i] = norm2_ref(x, y, z);
    }
    __syncthreads();
    const float* pq = xyz2 + ((size_t)b * N2 + n) * 3;
    const float ax = pq[0], ay = pq[1], az = pq[2];
    const float sa = norm2_ref(ax, ay, az);
    float d0 = FLT_MAX, d1 = FLT_MAX, d2 = FLT_MAX;
    int i0 = 0, i1 = 0, i2 = 0;
    const int jb = r << 8;
    for (int jj = 0; jj < 256; ++jj) {
        int j = jb + jj;
        float dist = dist_ref(sa, snb[j], ax, ay, az, sx[j], sy[j], sz[j]);
        if (dist < d2) {
            if (dist < d1) {
                d2 = d1; i2 = i1;
                if (dist < d0) { d1 = d0; i1 = i0; d0 = dist; i0 = j; }
                else           { d1 = dist; i1 = j; }
            } else { d2 = dist; i2 = j; }
        }
    }
    sd[ql][r][0] = d0; sd[ql][r][1] = d1; sd[ql][r][2] = d2;
    si[ql][r][0] = i0; si[ql][r][1] = i1; si[ql][r][2] = i2;
    __syncthreads();
    if (r == 0) {
        int p0 = 0, p1 = 0, p2 = 0, p3 = 0;
        float md[3]; int mi[3];
        for (int o = 0; o < 3; ++o) {
            float h0 = (p0 < 3) ? sd[ql][0][p0] : FLT_MAX;
            float h1 = (p1 < 3) ? sd[ql][1][p1] : FLT_MAX;
            float h2 = (p2 < 3) ? sd[ql][2][p2] : FLT_MAX;
            float h3 = (p3 < 3) ? sd[ql][3][p3] : FLT_MAX;
            int br = 0; float bd = h0;
            if (h1 < bd) { bd = h1; br = 1; }
            if (h2 < bd) { bd = h2; br = 2; }
            if (h3 < bd) { bd = h3; br = 3; }
            if (br == 0)      { mi[o] = si[ql][0][p0]; md[o] = h0; ++p0; }
            else if (br == 1) { mi[o] = si[ql][1][p1]; md[o] = h1; ++p1; }
            else if (br == 2) { mi[o] = si[ql][2][p2]; md[o] = h2; ++p2; }
            else              { mi[o] = si[ql][3][p3]; md[o] = h3; ++p3; }
        }
        float r0 = __fdiv_rn(1.f, __fadd_rn(md[0], 1e-8f));
        float r1 = __fdiv_rn(1.f, __fadd_rn(md[1], 1e-8f));
        float r2 = __fdiv_rn(1.f, __fadd_rn(md[2], 1e-8f));
        float s  = __fadd_rn(__fadd_rn(r0, r1), r2);
        sw[ql][0] = __fdiv_rn(r0, s);
        sw[ql][1] = __fdiv_rn(r1, s);
        sw[ql][2] = __fdiv_rn(r2, s);
        sidx[ql][0] = mi[0]; sidx[ql][1] = mi[1]; sidx[ql][2] = mi[2];
    }
    __syncthreads();
    const float* f1b = f1 + (size_t)b * N1 * 256;
    for (int p = 0; p < 64; ++p) {
        int bn = (b << 12) + q0 + p;
        float w0 = sw[p][0], w1 = sw[p][1], w2 = sw[p][2];
        int j0 = sidx[p][0], j1 = sidx[p][1], j2 = sidx[p][2];
        float itp = w0 * f1b[(size_t)j0 * 256 + tid]
                  + w1 * f1b[(size_t)j1 * 256 + tid]
                  + w2 * f1b[(size_t)j2 * 256 + tid];
        feats[(size_t)bn * 256 + tid] = bf16r(bf16r(itp) + feats[(size_t)bn * 256 + tid]);
    }
}

// ---------------------------------------------------------------------------
// KNN top-16: EXACT round-17 selection (same candidate order, same insertion,
// same merge — bit-identical output). Only the LDS layout changed: +8 floats
// of padding per 1024-range puts the 4 ranges on 4 distinct banks
// (word offsets {0,1032,2064,3096} mod 32 = {0,8,16,24}) -> conflict-free.
// ---------------------------------------------------------------------------
#define KPAD(j) ((j) + (((j) >> 10) << 3))

__global__ __launch_bounds__(256) void knn_kernel(
    const float* __restrict__ xyz2, int* __restrict__ knn_out)
{
    const int b = blockIdx.x >> 6;
    const int q0 = (blockIdx.x & 63) << 6;
    const int tid = threadIdx.x;
    const int ql = tid >> 2, r = tid & 3;
    const int n = q0 + ql;
    __shared__ float sx[N2 + 32], sy[N2 + 32], sz[N2 + 32], sn[N2 + 32];
    __shared__ float sd[64][4][16];
    __shared__ int   si[64][4][16];
    for (int i = tid; i < N2; i += 256) {
        int st = KPAD(i);
        const float* p = xyz2 + ((size_t)b * N2 + i) * 3;
        float x = p[0], y = p[1], z = p[2];
        sx[st] = x; sy[st] = y; sz[st] = z;
        sn[st] = norm2_ref(x, y, z);
    }
    __syncthreads();
    const int nst = KPAD(n);
    const float ax = sx[nst], ay = sy[nst], az = sz[nst];
    const float sa = sn[nst];
    float d[16]; int id[16];
#pragma unroll
    for (int s = 0; s < 16; ++s) { d[s] = FLT_MAX; id[s] = 0; }
    const int jbase = r << 10;
    const int sbase = KPAD(jbase);
    for (int jj = 0; jj < 1024; ++jj) {
        int st = sbase + jj;
        float dist = dist_ref(sa, sn[st], ax, ay, az, sx[st], sy[st], sz[st]);
        if (dist < d[15]) {
            int j = jbase + jj;
#pragma unroll
            for (int s = 15; s >= 0; --s) {
                bool shift = (s > 0) && (dist < d[s - 1]);
                bool place = (dist < d[s]) && !shift;
                float nd = shift ? d[s - 1] : (place ? dist : d[s]);
                int   ni = shift ? id[s - 1] : (place ? j : id[s]);
                d[s] = nd; id[s] = ni;
            }
        }
    }
#pragma unroll
    for (int s = 0; s < 16; ++s) { sd[ql][r][s] = d[s]; si[ql][r][s] = id[s]; }
    __syncthreads();
    if (r == 0) {
        int p0 = 0, p1 = 0, p2 = 0, p3 = 0;
        size_t ob = ((size_t)b * N2 + n) * 16;
        for (int o = 0; o < 16; ++o) {
            float h0 = (p0 < 16) ? sd[ql][0][p0] : FLT_MAX;
            float h1 = (p1 < 16) ? sd[ql][1][p1] : FLT_MAX;
            float h2 = (p2 < 16) ? sd[ql][2][p2] : FLT_MAX;
            float h3 = (p3 < 16) ? sd[ql][3][p3] : FLT_MAX;
            int br = 0; float bd = h0;
            if (h1 < bd) { bd = h1; br = 1; }
            if (h2 < bd) { bd = h2; br = 2; }
            if (h3 < bd) { bd = h3; br = 3; }
            int bi;
            if (br == 0)      { bi = si[ql][0][p0]; ++p0; }
            else if (br == 1) { bi = si[ql][1][p1]; ++p1; }
            else if (br == 2) { bi = si[ql][2][p2]; ++p2; }
            else              { bi = si[ql][3][p3]; ++p3; }
            knn_out[ob + o] = bi;
        }
    }
}

// ---------------------------------------------------------------------------
// MFMA attention, 2 points per block (unchanged — bit-identical, ~252 us)
// ---------------------------------------------------------------------------
__global__ __launch_bounds__(256) void attn_mfma2(
    const float* __restrict__ xyz2, const float* __restrict__ qg,
    const float* __restrict__ kg, const float* __restrict__ vg,
    const int* __restrict__ knn,
    const float* __restrict__ d1w, const float* __restrict__ d1b,
    const float* __restrict__ d2b, const float* __restrict__ g1b,
    const float* __restrict__ g2b,
    const unsigned short* __restrict__ Bd2,
    const unsigned short* __restrict__ Bg1,
    const unsigned short* __restrict__ Bg2,
    float* __restrict__ res)
{
    const int bn0 = blockIdx.x * PPB;
    const int b = bn0 >> 12;
    const int c = threadIdx.x;
    const int l = c & 63, wv_ = c >> 6;
    const int lr = l & 15, lg = l >> 4;

    __shared__ __align__(16) unsigned short phb[PPB * 16][264];
    __shared__ __align__(16) unsigned short posb[PPB * 16][264];
    __shared__ int   knn_s[PPB][16];
    __shared__ float relx[PPB][16], rely[PPB][16], relz[PPB][16];

    if (c < PPB * 16) {
        int p = c >> 4, kk = c & 15;
        int idx = knn[(size_t)(bn0 + p) * 16 + kk];
        knn_s[p][kk] = idx;
        const float* pq = xyz2 + (size_t)(bn0 + p) * 3;
        const float* pk = xyz2 + ((size_t)b * N2 + idx) * 3;
        relx[p][kk] = bf16r(pq[0] - pk[0]);
        rely[p][kk] = bf16r(pq[1] - pk[1]);
        relz[p][kk] = bf16r(pq[2] - pk[2]);
    }
    __syncthreads();

    const size_t basebc = (size_t)b * N2 * 256;
    float kf[PPB][16], qv[PPB];
#pragma unroll
    for (int p = 0; p < PPB; ++p) {
        qv[p] = qg[(size_t)(bn0 + p) * 256 + c];
#pragma unroll
        for (int kk = 0; kk < 16; ++kk)
            kf[p][kk] = kg[basebc + (size_t)knn_s[p][kk] * 256 + c];
    }

    {
        float w0 = bf16r(d1w[c]), w1 = bf16r(d1w[256 + c]), w2 = bf16r(d1w[512 + c]);
        float bb = d1b[c];
#pragma unroll
        for (int p = 0; p < PPB; ++p)
#pragma unroll
            for (int kk = 0; kk < 16; ++kk) {
                float v = fmaf(relx[p][kk], w0, fmaf(rely[p][kk], w1, fmaf(relz[p][kk], w2, bb)));
                phb[p * 16 + kk][c] = f2bu(fmaxf(v, 0.f));
            }
    }
    __syncthreads();

    f32x4 acc[PPB][4];
#pragma unroll
    for (int p = 0; p < PPB; ++p)
#pragma unroll
        for (int t = 0; t < 4; ++t) acc[p][t] = (f32x4){0.f, 0.f, 0.f, 0.f};
    for (int kb = 0; kb < 8; ++kb) {
        bf16x8 bfr[4];
#pragma unroll
        for (int t = 0; t < 4; ++t)
            bfr[t] = *(const bf16x8*)&Bd2[((size_t)(kb * 16 + wv_ * 4 + t) * 64 + l) * 8];
#pragma unroll
        for (int p = 0; p < PPB; ++p) {
            bf16x8 af = *(const bf16x8*)&phb[p * 16 + lr][kb * 32 + lg * 8];
#pragma unroll
            for (int t = 0; t < 4; ++t)
                acc[p][t] = __builtin_amdgcn_mfma_f32_16x16x32_bf16(af, bfr[t], acc[p][t], 0, 0, 0);
        }
    }
#pragma unroll
    for (int p = 0; p < PPB; ++p)
#pragma unroll
        for (int t = 0; t < 4; ++t) {
            int col = (wv_ * 4 + t) * 16 + lr;
            float bb = d2b[col];
#pragma unroll
            for (int r = 0; r < 4; ++r)
                posb[p * 16 + lg * 4 + r][col] = f2bu(acc[p][t][r] + bb);
        }
    __syncthreads();

    float posr[PPB][16];
#pragma unroll
    for (int p = 0; p < PPB; ++p)
#pragma unroll
        for (int kk = 0; kk < 16; ++kk) posr[p][kk] = bu2f(posb[p * 16 + kk][c]);
#pragma unroll
    for (int p = 0; p < PPB; ++p)
#pragma unroll
        for (int kk = 0; kk < 16; ++kk)
            phb[p * 16 + kk][c] = f2bu(bf16r(qv[p] - kf[p][kk]) + posr[p][kk]);
    __syncthreads();

#pragma unroll
    for (int p = 0; p < PPB; ++p)
#pragma unroll
        for (int t = 0; t < 4; ++t) acc[p][t] = (f32x4){0.f, 0.f, 0.f, 0.f};
    for (int kb = 0; kb < 8; ++kb) {
        bf16x8 bfr[4];
#pragma unroll
        for (int t = 0; t < 4; ++t)
            bfr[t] = *(const bf16x8*)&Bg1[((size_t)(kb * 16 + wv_ * 4 + t) * 64 + l) * 8];
#pragma unroll
        for (int p = 0; p < PPB; ++p) {
            bf16x8 af = *(const bf16x8*)&phb[p * 16 + lr][kb * 32 + lg * 8];
#pragma unroll
            for (int t = 0; t < 4; ++t)
                acc[p][t] = __builtin_amdgcn_mfma_f32_16x16x32_bf16(af, bfr[t], acc[p][t], 0, 0, 0);
        }
    }
    __syncthreads();
#pragma unroll
    for (int p = 0; p < PPB; ++p)
#pragma unroll
        for (int t = 0; t < 4; ++t) {
            int col = (wv_ * 4 + t) * 16 + lr;
            float bb = g1b[col];
#pragma unroll
            for (int r = 0; r < 4; ++r)
                phb[p * 16 + lg * 4 + r][col] = f2bu(fmaxf(acc[p][t][r] + bb, 0.f));
        }
    __syncthreads();

#pragma unroll
    for (int p = 0; p < PPB; ++p)
#pragma unroll
        for (int t = 0; t < 4; ++t) acc[p][t] = (f32x4){0.f, 0.f, 0.f, 0.f};
    for (int kb = 0; kb < 8; ++kb) {
        bf16x8 bfr[4];
#pragma unroll
        for (int t = 0; t < 4; ++t)
            bfr[t] = *(const bf16x8*)&Bg2[((size_t)(kb * 16 + wv_ * 4 + t) * 64 + l) * 8];
#pragma unroll
        for (int p = 0; p < PPB; ++p) {
            bf16x8 af = *(const bf16x8*)&phb[p * 16 + lr][kb * 32 + lg * 8];
#pragma unroll
            for (int t = 0; t < 4; ++t)
                acc[p][t] = __builtin_amdgcn_mfma_f32_16x16x32_bf16(af, bfr[t], acc[p][t], 0, 0, 0);
        }
    }
#pragma unroll
    for (int p = 0; p < PPB; ++p)
#pragma unroll
        for (int t = 0; t < 4; ++t) {
            int col = (wv_ * 4 + t) * 16 + lr;
            float bb = g2b[col];
#pragma unroll
            for (int r = 0; r < 4; ++r)
                posb[p * 16 + lg * 4 + r][col] = f2bu(acc[p][t][r] + bb);
        }
    __syncthreads();

#pragma unroll
    for (int p = 0; p < PPB; ++p) {
        float av[16];
#pragma unroll
        for (int kk = 0; kk < 16; ++kk) av[kk] = bu2f(posb[p * 16 + kk][c]) * 0.0625f;
        float m = av[0];
#pragma unroll
        for (int kk = 1; kk < 16; ++kk) m = fmaxf(m, av[kk]);
        float e[16];
        float s = 0.f;
#pragma unroll
        for (int kk = 0; kk < 16; ++kk) {
            e[kk] = bf16r(expf(av[kk] - m));
            s += e[kk];
        }
#pragma unroll
        for (int kk = 0; kk < 16; ++kk) e[kk] = bf16r(e[kk] / s);
        float rr = 0.f;
#pragma unroll
        for (int kk = 0; kk < 16; ++kk) {
            float vfv = vg[basebc + (size_t)knn_s[p][kk] * 256 + c];
            float vp = bf16r(vfv + posr[p][kk]);
            rr = fmaf(e[kk], vp, rr);
        }
        res[(size_t)(bn0 + p) * 256 + c] = bf16r(rr);
    }
}

// ---------------------------------------------------------------------------
extern "C" void kernel_launch(void* const* d_in, const int* in_sizes, int n_in,
                              void* d_out, int out_size, void* d_ws, size_t ws_size,
                              hipStream_t stream)
{
    const float* xyz1     = (const float*)d_in[0];
    const float* points1  = (const float*)d_in[1];
    const float* xyz2     = (const float*)d_in[2];
    const float* points2  = (const float*)d_in[3];
    const float* up_w1    = (const float*)d_in[4];
    const float* up_b1    = (const float*)d_in[5];
    const float* up_w2    = (const float*)d_in[6];
    const float* up_b2    = (const float*)d_in[7];
    const float* fc1_w    = (const float*)d_in[8];
    const float* fc1_b    = (const float*)d_in[9];
    const float* fc2_w    = (const float*)d_in[10];
    const float* fc2_b    = (const float*)d_in[11];
    const float* delta_w1 = (const float*)d_in[12];
    const float* delta_b1 = (const float*)d_in[13];
    const float* delta_w2 = (const float*)d_in[14];
    const float* delta_b2 = (const float*)d_in[15];
    const float* gamma_w1 = (const float*)d_in[16];
    const float* gamma_b1 = (const float*)d_in[17];
    const float* gamma_w2 = (const float*)d_in[18];
    const float* gamma_b2 = (const float*)d_in[19];
    const float* wq       = (const float*)d_in[20];
    const float* wk       = (const float*)d_in[21];
    const float* wv       = (const float*)d_in[22];

    float* ws = (float*)d_ws;
    float* f1    = ws;
    float* feats = f1 + (size_t)BB * N1 * 256;
    float* x     = feats + (size_t)BB * N2 * 256;
    float* qb    = x + (size_t)BB * N2 * 256;
    float* kb    = qb + (size_t)BB * N2 * 256;
    float* vb    = kb + (size_t)BB * N2 * 256;
    int*   knn   = (int*)(vb + (size_t)BB * N2 * 256);
    unsigned short* Bd2  = (unsigned short*)(knn + (size_t)BB * N2 * 16);
    unsigned short* Bg1  = Bd2 + 65536;
    unsigned short* Bg2  = Bg1 + 65536;
    unsigned short* Bup1 = Bg2 + 65536;
    unsigned short* Bup2 = Bup1 + 131072;
    unsigned short* Bfc1 = Bup2 + 65536;
    unsigned short* Bfc2 = Bfc1 + 65536;
    unsigned short* Bq   = Bfc2 + 65536;
    unsigned short* Bk   = Bq + 65536;
    unsigned short* Bv   = Bk + 65536;
    float* resb = x;   // x dead after q/k/v

    float* out = (float*)d_out;
    hipMemcpyAsync(out, xyz2, (size_t)BB * N2 * 3 * sizeof(float),
                   hipMemcpyDeviceToDevice, stream);

    const float BN = (float)(1.0 / sqrt(1.0 + 1e-5));

    SwzArgs sa;
    sa.W[0] = up_w1;    sa.B[0] = Bup1; sa.K[0] = CIN;
    sa.W[1] = up_w2;    sa.B[1] = Bup2; sa.K[1] = CC;
    sa.W[2] = fc1_w;    sa.B[2] = Bfc1; sa.K[2] = CC;
    sa.W[3] = fc2_w;    sa.B[3] = Bfc2; sa.K[3] = CC;
    sa.W[4] = wq;       sa.B[4] = Bq;   sa.K[4] = CC;
    sa.W[5] = wk;       sa.B[5] = Bk;   sa.K[5] = CC;
    sa.W[6] = wv;       sa.B[6] = Bv;   sa.K[6] = CC;
    sa.W[7] = delta_w2; sa.B[7] = Bd2;  sa.K[7] = CC;
    sa.W[8] = gamma_w1; sa.B[8] = Bg1;  sa.K[8] = CC;
    sa.W[9] = gamma_w2; sa.B[9] = Bg2;  sa.K[9] = CC;
    swizzle_all<<<dim3(64, 10), 256, 0, stream>>>(sa);

    gemm_mfma<CC, 8, true, true, false><<<BB * N2 / 64 * 2, 256, 0, stream>>>(
        points2, Bup2, up_b2, nullptr, BN, feats);
    gemm_mfma<CIN, 4, true, true, false><<<BB * N1 / 64 * 4, 256, 0, stream>>>(
        points1, Bup1, up_b1, nullptr, BN, f1);
    nn3_interp_kernel<<<BB * 64, 256, 0, stream>>>(xyz1, xyz2, f1, feats);
    gemm_mfma<CC, 8, false, false, false><<<BB * N2 / 64 * 2, 256, 0, stream>>>(
        feats, Bfc1, fc1_b, nullptr, 1.f, x);
    qkv_mfma<<<BB * N2 / 64 * 2, 256, 0, stream>>>(x, Bq, Bk, Bv, qb, kb, vb);
    knn_kernel<<<BB * 64, 256, 0, stream>>>(xyz2, knn);
    attn_mfma2<<<BB * N2 / PPB, 256, 0, stream>>>(xyz2, qb, kb, vb, knn,
                                                  delta_w1, delta_b1, delta_b2, gamma_b1, gamma_b2,
                                                  Bd2, Bg1, Bg2, resb);
    gemm_mfma<CC, 8, false, false, true><<<BB * N2 / 64 * 2, 256, 0, stream>>>(
        resb, Bfc2, fc2_b, feats, 1.f, out + (size_t)BB * N2 * 3);
}

// Round 20
// 631.256 us; speedup vs baseline: 1.3540x; 1.0051x over previous
//
#include <hip/hip_runtime.h>
#include <hip/hip_bf16.h>
#include <math.h>
#include <float.h>

#define BB   4
#define N1   1024
#define N2   4096
#define CIN  512
#define CC   256
#define DM   256
#define KNNK 16
#define PPB  2

typedef __attribute__((ext_vector_type(8))) short bf16x8;
typedef __attribute__((ext_vector_type(4))) float f32x4;

__device__ __forceinline__ float bf16r(float x) {
    return __bfloat162float(__float2bfloat16(x));
}
__device__ __forceinline__ unsigned short f2bu(float x) {
    __hip_bfloat16 h = __float2bfloat16(x);
    return *reinterpret_cast<unsigned short*>(&h);
}
__device__ __forceinline__ float bu2f(unsigned short u) {
    __hip_bfloat16 h = *reinterpret_cast<__hip_bfloat16*>(&u);
    return __bfloat162float(h);
}

// ---------------------------------------------------------------------------
// All 10 weight swizzles in one launch.
// ---------------------------------------------------------------------------
struct SwzArgs {
    const float* W[10];
    unsigned short* B[10];
    int K[10];
};
__global__ __launch_bounds__(256) void swizzle_all(SwzArgs a)
{
    int m = blockIdx.y;
    int idx = blockIdx.x * 256 + threadIdx.x;
    int total = (a.K[m] >> 5) << 10;
    if (idx >= total) return;
    const float* W = a.W[m];
    unsigned short* B = a.B[m];
    int l = idx & 63;
    int tile = (idx >> 6) & 15;
    int kb = idx >> 10;
    int col = tile * 16 + (l & 15);
    int k0 = kb * 32 + ((l >> 4) << 3);
#pragma unroll
    for (int i = 0; i < 8; ++i)
        B[(size_t)idx * 8 + i] = f2bu(W[(size_t)(k0 + i) * 256 + col]);
}

// ---------------------------------------------------------------------------
// MFMA GEMM, N-split (unchanged — bit-identical)
// ---------------------------------------------------------------------------
template<int KD, int NT, bool RELU, bool BN_, bool RESID>
__global__ __launch_bounds__(256) void gemm_mfma(
    const float* __restrict__ X, const unsigned short* __restrict__ Bw,
    const float* __restrict__ bias, const float* __restrict__ resid,
    float scale, float* __restrict__ Y)
{
    const int NSPLIT = 16 / NT;
    const int c = threadIdx.x;
    const int l = c & 63, wv_ = c >> 6;
    const int lr = l & 15, lg = l >> 4;
    const int row0 = (blockIdx.x / NSPLIT) * 64;
    const int tb = (blockIdx.x % NSPLIT) * NT;
    __shared__ __align__(16) unsigned short As[64][72];

    f32x4 acc[NT];
#pragma unroll
    for (int t = 0; t < NT; ++t) acc[t] = (f32x4){0.f, 0.f, 0.f, 0.f};

    const int rs = c >> 2, c0 = (c & 3) * 16;
    for (int ks = 0; ks < KD / 64; ++ks) {
        const float* src = X + (size_t)(row0 + rs) * KD + ks * 64 + c0;
#pragma unroll
        for (int i = 0; i < 16; i += 4) {
            float4 v = *(const float4*)(src + i);
            As[rs][c0 + i + 0] = f2bu(v.x);
            As[rs][c0 + i + 1] = f2bu(v.y);
            As[rs][c0 + i + 2] = f2bu(v.z);
            As[rs][c0 + i + 3] = f2bu(v.w);
        }
        __syncthreads();
#pragma unroll
        for (int kbl = 0; kbl < 2; ++kbl) {
            int kb = ks * 2 + kbl;
            bf16x8 af = *(const bf16x8*)&As[wv_ * 16 + lr][kbl * 32 + lg * 8];
#pragma unroll
            for (int t = 0; t < NT; ++t) {
                bf16x8 bf = *(const bf16x8*)&Bw[((size_t)(kb * 16 + tb + t) * 64 + l) * 8];
                acc[t] = __builtin_amdgcn_mfma_f32_16x16x32_bf16(af, bf, acc[t], 0, 0, 0);
            }
        }
        __syncthreads();
    }
#pragma unroll
    for (int t = 0; t < NT; ++t) {
        int col = (tb + t) * 16 + lr;
        float bb = bias ? bias[col] : 0.f;
#pragma unroll
        for (int r = 0; r < 4; ++r) {
            size_t row = row0 + wv_ * 16 + lg * 4 + r;
            float v = bf16r(acc[t][r]);
            v = bf16r(v + bb);
            if (BN_) v = bf16r(v * scale);
            if (RELU) v = fmaxf(v, 0.f);
            if (RESID) v = bf16r(v + resid[row * 256 + col]);
            Y[row * 256 + col] = v;
        }
    }
}

// ---------------------------------------------------------------------------
// Fused q/k/v GEMM (unchanged — bit-identical)
// ---------------------------------------------------------------------------
__global__ __launch_bounds__(256) void qkv_mfma(
    const float* __restrict__ X,
    const unsigned short* __restrict__ Bq,
    const unsigned short* __restrict__ Bk,
    const unsigned short* __restrict__ Bv,
    float* __restrict__ Yq, float* __restrict__ Yk, float* __restrict__ Yv)
{
    const int NT = 8;
    const int c = threadIdx.x;
    const int l = c & 63, wv_ = c >> 6;
    const int lr = l & 15, lg = l >> 4;
    const int row0 = (blockIdx.x >> 1) * 64;
    const int tb = (blockIdx.x & 1) * NT;
    __shared__ __align__(16) unsigned short As[64][72];

    f32x4 aq[NT], ak[NT], av_[NT];
#pragma unroll
    for (int t = 0; t < NT; ++t) {
        aq[t] = (f32x4){0.f, 0.f, 0.f, 0.f};
        ak[t] = aq[t]; av_[t] = aq[t];
    }

    const int rs = c >> 2, c0 = (c & 3) * 16;
    for (int ks = 0; ks < CC / 64; ++ks) {
        const float* src = X + (size_t)(row0 + rs) * CC + ks * 64 + c0;
#pragma unroll
        for (int i = 0; i < 16; i += 4) {
            float4 v = *(const float4*)(src + i);
            As[rs][c0 + i + 0] = f2bu(v.x);
            As[rs][c0 + i + 1] = f2bu(v.y);
            As[rs][c0 + i + 2] = f2bu(v.z);
            As[rs][c0 + i + 3] = f2bu(v.w);
        }
        __syncthreads();
#pragma unroll
        for (int kbl = 0; kbl < 2; ++kbl) {
            int kb = ks * 2 + kbl;
            bf16x8 af = *(const bf16x8*)&As[wv_ * 16 + lr][kbl * 32 + lg * 8];
#pragma unroll
            for (int t = 0; t < NT; ++t) {
                size_t fo = ((size_t)(kb * 16 + tb + t) * 64 + l) * 8;
                bf16x8 bq = *(const bf16x8*)&Bq[fo];
                bf16x8 bk = *(const bf16x8*)&Bk[fo];
                bf16x8 bv = *(const bf16x8*)&Bv[fo];
                aq[t]  = __builtin_amdgcn_mfma_f32_16x16x32_bf16(af, bq, aq[t], 0, 0, 0);
                ak[t]  = __builtin_amdgcn_mfma_f32_16x16x32_bf16(af, bk, ak[t], 0, 0, 0);
                av_[t] = __builtin_amdgcn_mfma_f32_16x16x32_bf16(af, bv, av_[t], 0, 0, 0);
            }
        }
        __syncthreads();
    }
#pragma unroll
    for (int t = 0; t < NT; ++t) {
        int col = (tb + t) * 16 + lr;
#pragma unroll
        for (int r = 0; r < 4; ++r) {
            size_t row = row0 + wv_ * 16 + lg * 4 + r;
            Yq[row * 256 + col] = bf16r(aq[t][r]);
            Yk[row * 256 + col] = bf16r(ak[t][r]);
            Yv[row * 256 + col] = bf16r(av_[t][r]);
        }
    }
}

// ---- faithful fp32 distance (selection on RAW fp32 coords) ---------------
__device__ __forceinline__ float norm2_ref(float x, float y, float z) {
    return __fadd_rn(__fadd_rn(__fmul_rn(x, x), __fmul_rn(y, y)), __fmul_rn(z, z));
}
__device__ __forceinline__ float dist_ref(float sa, float nb,
                                          float ax, float ay, float az,
                                          float bx, float by, float bz) {
    float dot = __fadd_rn(__fadd_rn(__fmul_rn(ax, bx), __fmul_rn(ay, by)),
                          __fmul_rn(az, bz));
    return __fsub_rn(__fadd_rn(sa, nb), __fmul_rn(2.f, dot));
}

// pack xyz2 coords + norm into float4 (values identical to LDS staging)
__global__ __launch_bounds__(256) void pack_kernel(
    const float* __restrict__ xyz2, float4* __restrict__ pk)
{
    int i = blockIdx.x * 256 + threadIdx.x;     // 0 .. BB*N2-1
    if (i >= BB * N2) return;
    const float* p = xyz2 + (size_t)i * 3;
    float x = p[0], y = p[1], z = p[2];
    pk[i] = make_float4(x, y, z, norm2_ref(x, y, z));
}

// ---------------------------------------------------------------------------
// 3-NN + fused interpolation (unchanged — bit-identical selection)
// ---------------------------------------------------------------------------
__global__ __launch_bounds__(256) void nn3_interp_kernel(
    const float* __restrict__ xyz1, const float* __restrict__ xyz2,
    const float* __restrict__ f1, float* __restrict__ feats)
{
    const int b = blockIdx.x >> 6;
    const int q0 = (blockIdx.x & 63) << 6;
    const int tid = threadIdx.x;
    const int ql = tid >> 2, r = tid & 3;
    const int n = q0 + ql;
    __shared__ float sx[N1], sy[N1], sz[N1], snb[N1];
    __shared__ float sd[64][4][3];
    __shared__ int   si[64][4][3];
    __shared__ float sw[64][3];
    __shared__ int   sidx[64][3];
    for (int i = tid; i < N1; i += 256) {
        const float* p = xyz1 + ((size_t)b * N1 + i) * 3;
        float x = p[0], y = p[1], z = p[2];
        sx[i] = x; sy[i] = y; sz[i] = z;
        snb[i] = norm2_ref(x, y, z);
    }
    __syncthreads();
    const float* pq = xyz2 + ((size_t)b * N2 + n) * 3;
    const float ax = pq[0], ay = pq[1], az = pq[2];
    const float sa = norm2_ref(ax, ay, az);
    float d0 = FLT_MAX, d1 = FLT_MAX, d2 = FLT_MAX;
    int i0 = 0, i1 = 0, i2 = 0;
    const int jb = r << 8;
    for (int jj = 0; jj < 256; ++jj) {
        int j = jb + jj;
        float dist = dist_ref(sa, snb[j], ax, ay, az, sx[j], sy[j], sz[j]);
        if (dist < d2) {
            if (dist < d1) {
                d2 = d1; i2 = i1;
                if (dist < d0) { d1 = d0; i1 = i0; d0 = dist; i0 = j; }
                else           { d1 = dist; i1 = j; }
            } else { d2 = dist; i2 = j; }
        }
    }
    sd[ql][r][0] = d0; sd[ql][r][1] = d1; sd[ql][r][2] = d2;
    si[ql][r][0] = i0; si[ql][r][1] = i1; si[ql][r][2] = i2;
    __syncthreads();
    if (r == 0) {
        int p0 = 0, p1 = 0, p2 = 0, p3 = 0;
        float md[3]; int mi[3];
        for (int o = 0; o < 3; ++o) {
            float h0 = (p0 < 3) ? sd[ql][0][p0] : FLT_MAX;
            float h1 = (p1 < 3) ? sd[ql][1][p1] : FLT_MAX;
            float h2 = (p2 < 3) ? sd[ql][2][p2] : FLT_MAX;
            float h3 = (p3 < 3) ? sd[ql][3][p3] : FLT_MAX;
            int br = 0; float bd = h0;
            if (h1 < bd) { bd = h1; br = 1; }
            if (h2 < bd) { bd = h2; br = 2; }
            if (h3 < bd) { bd = h3; br = 3; }
            if (br == 0)      { mi[o] = si[ql][0][p0]; md[o] = h0; ++p0; }
            else if (br == 1) { mi[o] = si[ql][1][p1]; md[o] = h1; ++p1; }
            else if (br == 2) { mi[o] = si[ql][2][p2]; md[o] = h2; ++p2; }
            else              { mi[o] = si[ql][3][p3]; md[o] = h3; ++p3; }
        }
        float r0 = __fdiv_rn(1.f, __fadd_rn(md[0], 1e-8f));
        float r1 = __fdiv_rn(1.f, __fadd_rn(md[1], 1e-8f));
        float r2 = __fdiv_rn(1.f, __fadd_rn(md[2], 1e-8f));
        float s  = __fadd_rn(__fadd_rn(r0, r1), r2);
        sw[ql][0] = __fdiv_rn(r0, s);
        sw[ql][1] = __fdiv_rn(r1, s);
        sw[ql][2] = __fdiv_rn(r2, s);
        sidx[ql][0] = mi[0]; sidx[ql][1] = mi[1]; sidx[ql][2] = mi[2];
    }
    __syncthreads();
    const float* f1b = f1 + (size_t)b * N1 * 256;
    for (int p = 0; p < 64; ++p) {
        int bn = (b << 12) + q0 + p;
        float w0 = sw[p][0], w1 = sw[p][1], w2 = sw[p][2];
        int j0 = sidx[p][0], j1 = sidx[p][1], j2 = sidx[p][2];
        float itp = w0 * f1b[(size_t)j0 * 256 + tid]
                  + w1 * f1b[(size_t)j1 * 256 + tid]
                  + w2 * f1b[(size_t)j2 * 256 + tid];
        feats[(size_t)bn * 256 + tid] = bf16r(bf16r(itp) + feats[(size_t)bn * 256 + tid]);
    }
}

// ---------------------------------------------------------------------------
// KNN top-16, 16-way INDEX-ALIGNED split. Bit-identical to the proven 4-way
// scan: per-thread stable strict-< insertion over contiguous ascending range
// [t*256,(t+1)*256) = lexicographic top-16 of that range; 16-way merge
// preferring the lowest t on exact ties = lexicographic merge. Lexicographic
// top-16 is partition-invariant for index-aligned partitions, so the output
// equals the 4-way (and full sequential) scan exactly.
// 1024 blocks (16 queries x 16 ranges = 256 thr), coords from packed global
// float4 (L2-resident), LDS = 32 KB -> 16 waves/CU (was 4).
// ---------------------------------------------------------------------------
__global__ __launch_bounds__(256) void knn_kernel(
    const float4* __restrict__ pk, int* __restrict__ knn_out)
{
    const int b = blockIdx.x >> 8;              // 256 blocks per batch
    const int q0 = (blockIdx.x & 255) << 4;     // 16 queries per block
    const int tid = threadIdx.x;
    const int ql = tid >> 4, t = tid & 15;
    const int n = q0 + ql;
    __shared__ float sd[16][16][16];
    __shared__ int   si[16][16][16];

    const float4* base = pk + (size_t)b * N2;
    float4 qp = base[n];
    const float ax = qp.x, ay = qp.y, az = qp.z, sa = qp.w;

    float d[16]; int id[16];
#pragma unroll
    for (int s = 0; s < 16; ++s) { d[s] = FLT_MAX; id[s] = 0; }
    const int jbase = t << 8;
    for (int jj = 0; jj < 256; ++jj) {
        int j = jbase + jj;
        float4 cp = base[j];
        float dist = dist_ref(sa, cp.w, ax, ay, az, cp.x, cp.y, cp.z);
        if (dist < d[15]) {
#pragma unroll
            for (int s = 15; s >= 0; --s) {
                bool shift = (s > 0) && (dist < d[s - 1]);
                bool place = (dist < d[s]) && !shift;
                float nd = shift ? d[s - 1] : (place ? dist : d[s]);
                int   ni = shift ? id[s - 1] : (place ? j : id[s]);
                d[s] = nd; id[s] = ni;
            }
        }
    }
#pragma unroll
    for (int s = 0; s < 16; ++s) { sd[ql][t][s] = d[s]; si[ql][t][s] = id[s]; }
    __syncthreads();
    if (t == 0) {
        int ptr[16];
#pragma unroll
        for (int u = 0; u < 16; ++u) ptr[u] = 0;
        size_t ob = ((size_t)b * N2 + n) * 16;
        for (int o = 0; o < 16; ++o) {
            int bu = 0;
            float bd = (ptr[0] < 16) ? sd[ql][0][ptr[0]] : FLT_MAX;
            for (int u = 1; u < 16; ++u) {
                float hu = (ptr[u] < 16) ? sd[ql][u][ptr[u]] : FLT_MAX;
                if (hu < bd) { bd = hu; bu = u; }   // strict < : lowest t wins ties
            }
            knn_out[ob + o] = si[ql][bu][ptr[bu]];
            ++ptr[bu];
        }
    }
}

// ---------------------------------------------------------------------------
// MFMA attention, 2 points per block (unchanged — bit-identical, ~252 us)
// ---------------------------------------------------------------------------
__global__ __launch_bounds__(256) void attn_mfma2(
    const float* __restrict__ xyz2, const float* __restrict__ qg,
    const float* __restrict__ kg, const float* __restrict__ vg,
    const int* __restrict__ knn,
    const float* __restrict__ d1w, const float* __restrict__ d1b,
    const float* __restrict__ d2b, const float* __restrict__ g1b,
    const float* __restrict__ g2b,
    const unsigned short* __restrict__ Bd2,
    const unsigned short* __restrict__ Bg1,
    const unsigned short* __restrict__ Bg2,
    float* __restrict__ res)
{
    const int bn0 = blockIdx.x * PPB;
    const int b = bn0 >> 12;
    const int c = threadIdx.x;
    const int l = c & 63, wv_ = c >> 6;
    const int lr = l & 15, lg = l >> 4;

    __shared__ __align__(16) unsigned short phb[PPB * 16][264];
    __shared__ __align__(16) unsigned short posb[PPB * 16][264];
    __shared__ int   knn_s[PPB][16];
    __shared__ float relx[PPB][16], rely[PPB][16], relz[PPB][16];

    if (c < PPB * 16) {
        int p = c >> 4, kk = c & 15;
        int idx = knn[(size_t)(bn0 + p) * 16 + kk];
        knn_s[p][kk] = idx;
        const float* pq = xyz2 + (size_t)(bn0 + p) * 3;
        const float* pk = xyz2 + ((size_t)b * N2 + idx) * 3;
        relx[p][kk] = bf16r(pq[0] - pk[0]);
        rely[p][kk] = bf16r(pq[1] - pk[1]);
        relz[p][kk] = bf16r(pq[2] - pk[2]);
    }
    __syncthreads();

    const size_t basebc = (size_t)b * N2 * 256;
    float kf[PPB][16], qv[PPB];
#pragma unroll
    for (int p = 0; p < PPB; ++p) {
        qv[p] = qg[(size_t)(bn0 + p) * 256 + c];
#pragma unroll
        for (int kk = 0; kk < 16; ++kk)
            kf[p][kk] = kg[basebc + (size_t)knn_s[p][kk] * 256 + c];
    }

    {
        float w0 = bf16r(d1w[c]), w1 = bf16r(d1w[256 + c]), w2 = bf16r(d1w[512 + c]);
        float bb = d1b[c];
#pragma unroll
        for (int p = 0; p < PPB; ++p)
#pragma unroll
            for (int kk = 0; kk < 16; ++kk) {
                float v = fmaf(relx[p][kk], w0, fmaf(rely[p][kk], w1, fmaf(relz[p][kk], w2, bb)));
                phb[p * 16 + kk][c] = f2bu(fmaxf(v, 0.f));
            }
    }
    __syncthreads();

    f32x4 acc[PPB][4];
#pragma unroll
    for (int p = 0; p < PPB; ++p)
#pragma unroll
        for (int t = 0; t < 4; ++t) acc[p][t] = (f32x4){0.f, 0.f, 0.f, 0.f};
    for (int kb = 0; kb < 8; ++kb) {
        bf16x8 bfr[4];
#pragma unroll
        for (int t = 0; t < 4; ++t)
            bfr[t] = *(const bf16x8*)&Bd2[((size_t)(kb * 16 + wv_ * 4 + t) * 64 + l) * 8];
#pragma unroll
        for (int p = 0; p < PPB; ++p) {
            bf16x8 af = *(const bf16x8*)&phb[p * 16 + lr][kb * 32 + lg * 8];
#pragma unroll
            for (int t = 0; t < 4; ++t)
                acc[p][t] = __builtin_amdgcn_mfma_f32_16x16x32_bf16(af, bfr[t], acc[p][t], 0, 0, 0);
        }
    }
#pragma unroll
    for (int p = 0; p < PPB; ++p)
#pragma unroll
        for (int t = 0; t < 4; ++t) {
            int col = (wv_ * 4 + t) * 16 + lr;
            float bb = d2b[col];
#pragma unroll
            for (int r = 0; r < 4; ++r)
                posb[p * 16 + lg * 4 + r][col] = f2bu(acc[p][t][r] + bb);
        }
    __syncthreads();

    float posr[PPB][16];
#pragma unroll
    for (int p = 0; p < PPB; ++p)
#pragma unroll
        for (int kk = 0; kk < 16; ++kk) posr[p][kk] = bu2f(posb[p * 16 + kk][c]);
#pragma unroll
    for (int p = 0; p < PPB; ++p)
#pragma unroll
        for (int kk = 0; kk < 16; ++kk)
            phb[p * 16 + kk][c] = f2bu(bf16r(qv[p] - kf[p][kk]) + posr[p][kk]);
    __syncthreads();

#pragma unroll
    for (int p = 0; p < PPB; ++p)
#pragma unroll
        for (int t = 0; t < 4; ++t) acc[p][t] = (f32x4){0.f, 0.f, 0.f, 0.f};
    for (int kb = 0; kb < 8; ++kb) {
        bf16x8 bfr[4];
#pragma unroll
        for (int t = 0; t < 4; ++t)
            bfr[t] = *(const bf16x8*)&Bg1[((size_t)(kb * 16 + wv_ * 4 + t) * 64 + l) * 8];
#pragma unroll
        for (int p = 0; p < PPB; ++p) {
            bf16x8 af = *(const bf16x8*)&phb[p * 16 + lr][kb * 32 + lg * 8];
#pragma unroll
            for (int t = 0; t < 4; ++t)
                acc[p][t] = __builtin_amdgcn_mfma_f32_16x16x32_bf16(af, bfr[t], acc[p][t], 0, 0, 0);
        }
    }
    __syncthreads();
#pragma unroll
    for (int p = 0; p < PPB; ++p)
#pragma unroll
        for (int t = 0; t < 4; ++t) {
            int col = (wv_ * 4 + t) * 16 + lr;
            float bb = g1b[col];
#pragma unroll
            for (int r = 0; r < 4; ++r)
                phb[p * 16 + lg * 4 + r][col] = f2bu(fmaxf(acc[p][t][r] + bb, 0.f));
        }
    __syncthreads();

#pragma unroll
    for (int p = 0; p < PPB; ++p)
#pragma unroll
        for (int t = 0; t < 4; ++t) acc[p][t] = (f32x4){0.f, 0.f, 0.f, 0.f};
    for (int kb = 0; kb < 8; ++kb) {
        bf16x8 bfr[4];
#pragma unroll
        for (int t = 0; t < 4; ++t)
            bfr[t] = *(const bf16x8*)&Bg2[((size_t)(kb * 16 + wv_ * 4 + t) * 64 + l) * 8];
#pragma unroll
        for (int p = 0; p < PPB; ++p) {
            bf16x8 af = *(const bf16x8*)&phb[p * 16 + lr][kb * 32 + lg * 8];
#pragma unroll
            for (int t = 0; t < 4; ++t)
                acc[p][t] = __builtin_amdgcn_mfma_f32_16x16x32_bf16(af, bfr[t], acc[p][t], 0, 0, 0);
        }
    }
#pragma unroll
    for (int p = 0; p < PPB; ++p)
#pragma unroll
        for (int t = 0; t < 4; ++t) {
            int col = (wv_ * 4 + t) * 16 + lr;
            float bb = g2b[col];
#pragma unroll
            for (int r = 0; r < 4; ++r)
                posb[p * 16 + lg * 4 + r][col] = f2bu(acc[p][t][r] + bb);
        }
    __syncthreads();

#pragma unroll
    for (int p = 0; p < PPB; ++p) {
        float av[16];
#pragma unroll
        for (int kk = 0; kk < 16; ++kk) av[kk] = bu2f(posb[p * 16 + kk][c]) * 0.0625f;
        float m = av[0];
#pragma unroll
        for (int kk = 1; kk < 16; ++kk) m = fmaxf(m, av[kk]);
        float e[16];
        float s = 0.f;
#pragma unroll
        for (int kk = 0; kk < 16; ++kk) {
            e[kk] = bf16r(expf(av[kk] - m));
            s += e[kk];
        }
#pragma unroll
        for (int kk = 0; kk < 16; ++kk) e[kk] = bf16r(e[kk] / s);
        float rr = 0.f;
#pragma unroll
        for (int kk = 0; kk < 16; ++kk) {
            float vfv = vg[basebc + (size_t)knn_s[p][kk] * 256 + c];
            float vp = bf16r(vfv + posr[p][kk]);
            rr = fmaf(e[kk], vp, rr);
        }
        res[(size_t)(bn0 + p) * 256 + c] = bf16r(rr);
    }
}

// ---------------------------------------------------------------------------
extern "C" void kernel_launch(void* const* d_in, const int* in_sizes, int n_in,
                              void* d_out, int out_size, void* d_ws, size_t ws_size,
                              hipStream_t stream)
{
    const float* xyz1     = (const float*)d_in[0];
    const float* points1  = (const float*)d_in[1];
    const float* xyz2     = (const float*)d_in[2];
    const float* points2  = (const float*)d_in[3];
    const float* up_w1    = (const float*)d_in[4];
    const float* up_b1    = (const float*)d_in[5];
    const float* up_w2    = (const float*)d_in[6];
    const float* up_b2    = (const float*)d_in[7];
    const float* fc1_w    = (const float*)d_in[8];
    const float* fc1_b    = (const float*)d_in[9];
    const float* fc2_w    = (const float*)d_in[10];
    const float* fc2_b    = (const float*)d_in[11];
    const float* delta_w1 = (const float*)d_in[12];
    const float* delta_b1 = (const float*)d_in[13];
    const float* delta_w2 = (const float*)d_in[14];
    const float* delta_b2 = (const float*)d_in[15];
    const float* gamma_w1 = (const float*)d_in[16];
    const float* gamma_b1 = (const float*)d_in[17];
    const float* gamma_w2 = (const float*)d_in[18];
    const float* gamma_b2 = (const float*)d_in[19];
    const float* wq       = (const float*)d_in[20];
    const float* wk       = (const float*)d_in[21];
    const float* wv       = (const float*)d_in[22];

    float* ws = (float*)d_ws;
    float* f1    = ws;
    float* feats = f1 + (size_t)BB * N1 * 256;
    float* x     = feats + (size_t)BB * N2 * 256;
    float* qb    = x + (size_t)BB * N2 * 256;
    float* kb    = qb + (size_t)BB * N2 * 256;
    float* vb    = kb + (size_t)BB * N2 * 256;
    int*   knn   = (int*)(vb + (size_t)BB * N2 * 256);
    unsigned short* Bd2  = (unsigned short*)(knn + (size_t)BB * N2 * 16);
    unsigned short* Bg1  = Bd2 + 65536;
    unsigned short* Bg2  = Bg1 + 65536;
    unsigned short* Bup1 = Bg2 + 65536;
    unsigned short* Bup2 = Bup1 + 131072;
    unsigned short* Bfc1 = Bup2 + 65536;
    unsigned short* Bfc2 = Bfc1 + 65536;
    unsigned short* Bq   = Bfc2 + 65536;
    unsigned short* Bk   = Bq + 65536;
    unsigned short* Bv   = Bk + 65536;
    float4* pkbuf = (float4*)(Bv + 65536);      // BB*N2 float4 = 256 KB
    float* resb = x;   // x dead after q/k/v

    float* out = (float*)d_out;
    hipMemcpyAsync(out, xyz2, (size_t)BB * N2 * 3 * sizeof(float),
                   hipMemcpyDeviceToDevice, stream);

    const float BN = (float)(1.0 / sqrt(1.0 + 1e-5));

    SwzArgs sa;
    sa.W[0] = up_w1;    sa.B[0] = Bup1; sa.K[0] = CIN;
    sa.W[1] = up_w2;    sa.B[1] = Bup2; sa.K[1] = CC;
    sa.W[2] = fc1_w;    sa.B[2] = Bfc1; sa.K[2] = CC;
    sa.W[3] = fc2_w;    sa.B[3] = Bfc2; sa.K[3] = CC;
    sa.W[4] = wq;       sa.B[4] = Bq;   sa.K[4] = CC;
    sa.W[5] = wk;       sa.B[5] = Bk;   sa.K[5] = CC;
    sa.W[6] = wv;       sa.B[6] = Bv;   sa.K[6] = CC;
    sa.W[7] = delta_w2; sa.B[7] = Bd2;  sa.K[7] = CC;
    sa.W[8] = gamma_w1; sa.B[8] = Bg1;  sa.K[8] = CC;
    sa.W[9] = gamma_w2; sa.B[9] = Bg2;  sa.K[9] = CC;
    swizzle_all<<<dim3(64, 10), 256, 0, stream>>>(sa);

    // pack coords+norms for knn
    pack_kernel<<<BB * N2 / 256, 256, 0, stream>>>(xyz2, pkbuf);

    gemm_mfma<CC, 8, true, true, false><<<BB * N2 / 64 * 2, 256, 0, stream>>>(
        points2, Bup2, up_b2, nullptr, BN, feats);
    gemm_mfma<CIN, 4, true, true, false><<<BB * N1 / 64 * 4, 256, 0, stream>>>(
        points1, Bup1, up_b1, nullptr, BN, f1);
    nn3_interp_kernel<<<BB * 64, 256, 0, stream>>>(xyz1, xyz2, f1, feats);
    gemm_mfma<CC, 8, false, false, false><<<BB * N2 / 64 * 2, 256, 0, stream>>>(
        feats, Bfc1, fc1_b, nullptr, 1.f, x);
    qkv_mfma<<<BB * N2 / 64 * 2, 256, 0, stream>>>(x, Bq, Bk, Bv, qb, kb, vb);
    // KNN, 16-way index-aligned split                        [1024 blocks]
    knn_kernel<<<BB * 256, 256, 0, stream>>>(pkbuf, knn);
    attn_mfma2<<<BB * N2 / PPB, 256, 0, stream>>>(xyz2, qb, kb, vb, knn,
                                                  delta_w1, delta_b1, delta_b2, gamma_b1, gamma_b2,
                                                  Bd2, Bg1, Bg2, resb);
    gemm_mfma<CC, 8, false, false, true><<<BB * N2 / 64 * 2, 256, 0, stream>>>(
        resb, Bfc2, fc2_b, feats, 1.f, out + (size_t)BB * N2 * 3);
}

// Round 21
// 589.610 us; speedup vs baseline: 1.4497x; 1.0706x over previous
//
#include <hip/hip_runtime.h>
#include <hip/hip_bf16.h>
#include <math.h>
#include <float.h>

#define BB   4
#define N1   1024
#define N2   4096
#define CIN  512
#define CC   256
#define DM   256
#define KNNK 16
#define PPB  2

typedef __attribute__((ext_vector_type(8))) short bf16x8;
typedef __attribute__((ext_vector_type(4))) float f32x4;

__device__ __forceinline__ float bf16r(float x) {
    return __bfloat162float(__float2bfloat16(x));
}
__device__ __forceinline__ unsigned short f2bu(float x) {
    __hip_bfloat16 h = __float2bfloat16(x);
    return *reinterpret_cast<unsigned short*>(&h);
}
__device__ __forceinline__ float bu2f(unsigned short u) {
    __hip_bfloat16 h = *reinterpret_cast<__hip_bfloat16*>(&u);
    return __bfloat162float(h);
}

// ---------------------------------------------------------------------------
// All 10 weight swizzles in one launch.
// ---------------------------------------------------------------------------
struct SwzArgs {
    const float* W[10];
    unsigned short* B[10];
    int K[10];
};
__global__ __launch_bounds__(256) void swizzle_all(SwzArgs a)
{
    int m = blockIdx.y;
    int idx = blockIdx.x * 256 + threadIdx.x;
    int total = (a.K[m] >> 5) << 10;
    if (idx >= total) return;
    const float* W = a.W[m];
    unsigned short* B = a.B[m];
    int l = idx & 63;
    int tile = (idx >> 6) & 15;
    int kb = idx >> 10;
    int col = tile * 16 + (l & 15);
    int k0 = kb * 32 + ((l >> 4) << 3);
#pragma unroll
    for (int i = 0; i < 8; ++i)
        B[(size_t)idx * 8 + i] = f2bu(W[(size_t)(k0 + i) * 256 + col]);
}

// ---------------------------------------------------------------------------
// MFMA GEMM, N-split (per-element arithmetic bit-identical for any NT)
// ---------------------------------------------------------------------------
template<int KD, int NT, bool RELU, bool BN_, bool RESID>
__global__ __launch_bounds__(256) void gemm_mfma(
    const float* __restrict__ X, const unsigned short* __restrict__ Bw,
    const float* __restrict__ bias, const float* __restrict__ resid,
    float scale, float* __restrict__ Y)
{
    const int NSPLIT = 16 / NT;
    const int c = threadIdx.x;
    const int l = c & 63, wv_ = c >> 6;
    const int lr = l & 15, lg = l >> 4;
    const int row0 = (blockIdx.x / NSPLIT) * 64;
    const int tb = (blockIdx.x % NSPLIT) * NT;
    __shared__ __align__(16) unsigned short As[64][72];

    f32x4 acc[NT];
#pragma unroll
    for (int t = 0; t < NT; ++t) acc[t] = (f32x4){0.f, 0.f, 0.f, 0.f};

    const int rs = c >> 2, c0 = (c & 3) * 16;
    for (int ks = 0; ks < KD / 64; ++ks) {
        const float* src = X + (size_t)(row0 + rs) * KD + ks * 64 + c0;
#pragma unroll
        for (int i = 0; i < 16; i += 4) {
            float4 v = *(const float4*)(src + i);
            As[rs][c0 + i + 0] = f2bu(v.x);
            As[rs][c0 + i + 1] = f2bu(v.y);
            As[rs][c0 + i + 2] = f2bu(v.z);
            As[rs][c0 + i + 3] = f2bu(v.w);
        }
        __syncthreads();
#pragma unroll
        for (int kbl = 0; kbl < 2; ++kbl) {
            int kb = ks * 2 + kbl;
            bf16x8 af = *(const bf16x8*)&As[wv_ * 16 + lr][kbl * 32 + lg * 8];
#pragma unroll
            for (int t = 0; t < NT; ++t) {
                bf16x8 bf = *(const bf16x8*)&Bw[((size_t)(kb * 16 + tb + t) * 64 + l) * 8];
                acc[t] = __builtin_amdgcn_mfma_f32_16x16x32_bf16(af, bf, acc[t], 0, 0, 0);
            }
        }
        __syncthreads();
    }
#pragma unroll
    for (int t = 0; t < NT; ++t) {
        int col = (tb + t) * 16 + lr;
        float bb = bias ? bias[col] : 0.f;
#pragma unroll
        for (int r = 0; r < 4; ++r) {
            size_t row = row0 + wv_ * 16 + lg * 4 + r;
            float v = bf16r(acc[t][r]);
            v = bf16r(v + bb);
            if (BN_) v = bf16r(v * scale);
            if (RELU) v = fmaxf(v, 0.f);
            if (RESID) v = bf16r(v + resid[row * 256 + col]);
            Y[row * 256 + col] = v;
        }
    }
}

// ---------------------------------------------------------------------------
// Fused q/k/v GEMM, NT=4 (1024 blocks; per-element arithmetic identical)
// ---------------------------------------------------------------------------
__global__ __launch_bounds__(256) void qkv_mfma(
    const float* __restrict__ X,
    const unsigned short* __restrict__ Bq,
    const unsigned short* __restrict__ Bk,
    const unsigned short* __restrict__ Bv,
    float* __restrict__ Yq, float* __restrict__ Yk, float* __restrict__ Yv)
{
    const int NT = 4;
    const int c = threadIdx.x;
    const int l = c & 63, wv_ = c >> 6;
    const int lr = l & 15, lg = l >> 4;
    const int row0 = (blockIdx.x >> 2) * 64;
    const int tb = (blockIdx.x & 3) * NT;
    __shared__ __align__(16) unsigned short As[64][72];

    f32x4 aq[NT], ak[NT], av_[NT];
#pragma unroll
    for (int t = 0; t < NT; ++t) {
        aq[t] = (f32x4){0.f, 0.f, 0.f, 0.f};
        ak[t] = aq[t]; av_[t] = aq[t];
    }

    const int rs = c >> 2, c0 = (c & 3) * 16;
    for (int ks = 0; ks < CC / 64; ++ks) {
        const float* src = X + (size_t)(row0 + rs) * CC + ks * 64 + c0;
#pragma unroll
        for (int i = 0; i < 16; i += 4) {
            float4 v = *(const float4*)(src + i);
            As[rs][c0 + i + 0] = f2bu(v.x);
            As[rs][c0 + i + 1] = f2bu(v.y);
            As[rs][c0 + i + 2] = f2bu(v.z);
            As[rs][c0 + i + 3] = f2bu(v.w);
        }
        __syncthreads();
#pragma unroll
        for (int kbl = 0; kbl < 2; ++kbl) {
            int kb = ks * 2 + kbl;
            bf16x8 af = *(const bf16x8*)&As[wv_ * 16 + lr][kbl * 32 + lg * 8];
#pragma unroll
            for (int t = 0; t < NT; ++t) {
                size_t fo = ((size_t)(kb * 16 + tb + t) * 64 + l) * 8;
                bf16x8 bq = *(const bf16x8*)&Bq[fo];
                bf16x8 bk = *(const bf16x8*)&Bk[fo];
                bf16x8 bv = *(const bf16x8*)&Bv[fo];
                aq[t]  = __builtin_amdgcn_mfma_f32_16x16x32_bf16(af, bq, aq[t], 0, 0, 0);
                ak[t]  = __builtin_amdgcn_mfma_f32_16x16x32_bf16(af, bk, ak[t], 0, 0, 0);
                av_[t] = __builtin_amdgcn_mfma_f32_16x16x32_bf16(af, bv, av_[t], 0, 0, 0);
            }
        }
        __syncthreads();
    }
#pragma unroll
    for (int t = 0; t < NT; ++t) {
        int col = (tb + t) * 16 + lr;
#pragma unroll
        for (int r = 0; r < 4; ++r) {
            size_t row = row0 + wv_ * 16 + lg * 4 + r;
            Yq[row * 256 + col] = bf16r(aq[t][r]);
            Yk[row * 256 + col] = bf16r(ak[t][r]);
            Yv[row * 256 + col] = bf16r(av_[t][r]);
        }
    }
}

// ---- faithful fp32 distance (selection on RAW fp32 coords) ---------------
__device__ __forceinline__ float norm2_ref(float x, float y, float z) {
    return __fadd_rn(__fadd_rn(__fmul_rn(x, x), __fmul_rn(y, y)), __fmul_rn(z, z));
}
__device__ __forceinline__ float dist_ref(float sa, float nb,
                                          float ax, float ay, float az,
                                          float bx, float by, float bz) {
    float dot = __fadd_rn(__fadd_rn(__fmul_rn(ax, bx), __fmul_rn(ay, by)),
                          __fmul_rn(az, bz));
    return __fsub_rn(__fadd_rn(sa, nb), __fmul_rn(2.f, dot));
}

// pack xyz2 coords + norm into float4 (values identical to LDS staging)
__global__ __launch_bounds__(256) void pack_kernel(
    const float* __restrict__ xyz2, float4* __restrict__ pk)
{
    int i = blockIdx.x * 256 + threadIdx.x;
    if (i >= BB * N2) return;
    const float* p = xyz2 + (size_t)i * 3;
    float x = p[0], y = p[1], z = p[2];
    pk[i] = make_float4(x, y, z, norm2_ref(x, y, z));
}

// ---------------------------------------------------------------------------
// 3-NN + fused interpolation (unchanged — bit-identical selection)
// ---------------------------------------------------------------------------
__global__ __launch_bounds__(256) void nn3_interp_kernel(
    const float* __restrict__ xyz1, const float* __restrict__ xyz2,
    const float* __restrict__ f1, float* __restrict__ feats)
{
    const int b = blockIdx.x >> 6;
    const int q0 = (blockIdx.x & 63) << 6;
    const int tid = threadIdx.x;
    const int ql = tid >> 2, r = tid & 3;
    const int n = q0 + ql;
    __shared__ float sx[N1], sy[N1], sz[N1], snb[N1];
    __shared__ float sd[64][4][3];
    __shared__ int   si[64][4][3];
    __shared__ float sw[64][3];
    __shared__ int   sidx[64][3];
    for (int i = tid; i < N1; i += 256) {
        const float* p = xyz1 + ((size_t)b * N1 + i) * 3;
        float x = p[0], y = p[1], z = p[2];
        sx[i] = x; sy[i] = y; sz[i] = z;
        snb[i] = norm2_ref(x, y, z);
    }
    __syncthreads();
    const float* pq = xyz2 + ((size_t)b * N2 + n) * 3;
    const float ax = pq[0], ay = pq[1], az = pq[2];
    const float sa = norm2_ref(ax, ay, az);
    float d0 = FLT_MAX, d1 = FLT_MAX, d2 = FLT_MAX;
    int i0 = 0, i1 = 0, i2 = 0;
    const int jb = r << 8;
    for (int jj = 0; jj < 256; ++jj) {
        int j = jb + jj;
        float dist = dist_ref(sa, snb[j], ax, ay, az, sx[j], sy[j], sz[j]);
        if (dist < d2) {
            if (dist < d1) {
                d2 = d1; i2 = i1;
                if (dist < d0) { d1 = d0; i1 = i0; d0 = dist; i0 = j; }
                else           { d1 = dist; i1 = j; }
            } else { d2 = dist; i2 = j; }
        }
    }
    sd[ql][r][0] = d0; sd[ql][r][1] = d1; sd[ql][r][2] = d2;
    si[ql][r][0] = i0; si[ql][r][1] = i1; si[ql][r][2] = i2;
    __syncthreads();
    if (r == 0) {
        int p0 = 0, p1 = 0, p2 = 0, p3 = 0;
        float md[3]; int mi[3];
        for (int o = 0; o < 3; ++o) {
            float h0 = (p0 < 3) ? sd[ql][0][p0] : FLT_MAX;
            float h1 = (p1 < 3) ? sd[ql][1][p1] : FLT_MAX;
            float h2 = (p2 < 3) ? sd[ql][2][p2] : FLT_MAX;
            float h3 = (p3 < 3) ? sd[ql][3][p3] : FLT_MAX;
            int br = 0; float bd = h0;
            if (h1 < bd) { bd = h1; br = 1; }
            if (h2 < bd) { bd = h2; br = 2; }
            if (h3 < bd) { bd = h3; br = 3; }
            if (br == 0)      { mi[o] = si[ql][0][p0]; md[o] = h0; ++p0; }
            else if (br == 1) { mi[o] = si[ql][1][p1]; md[o] = h1; ++p1; }
            else if (br == 2) { mi[o] = si[ql][2][p2]; md[o] = h2; ++p2; }
            else              { mi[o] = si[ql][3][p3]; md[o] = h3; ++p3; }
        }
        float r0 = __fdiv_rn(1.f, __fadd_rn(md[0], 1e-8f));
        float r1 = __fdiv_rn(1.f, __fadd_rn(md[1], 1e-8f));
        float r2 = __fdiv_rn(1.f, __fadd_rn(md[2], 1e-8f));
        float s  = __fadd_rn(__fadd_rn(r0, r1), r2);
        sw[ql][0] = __fdiv_rn(r0, s);
        sw[ql][1] = __fdiv_rn(r1, s);
        sw[ql][2] = __fdiv_rn(r2, s);
        sidx[ql][0] = mi[0]; sidx[ql][1] = mi[1]; sidx[ql][2] = mi[2];
    }
    __syncthreads();
    const float* f1b = f1 + (size_t)b * N1 * 256;
    for (int p = 0; p < 64; ++p) {
        int bn = (b << 12) + q0 + p;
        float w0 = sw[p][0], w1 = sw[p][1], w2 = sw[p][2];
        int j0 = sidx[p][0], j1 = sidx[p][1], j2 = sidx[p][2];
        float itp = w0 * f1b[(size_t)j0 * 256 + tid]
                  + w1 * f1b[(size_t)j1 * 256 + tid]
                  + w2 * f1b[(size_t)j2 * 256 + tid];
        feats[(size_t)bn * 256 + tid] = bf16r(bf16r(itp) + feats[(size_t)bn * 256 + tid]);
    }
}

// ---------------------------------------------------------------------------
// KNN top-16, 16-way index-aligned split (unchanged — bit-identical)
// ---------------------------------------------------------------------------
__global__ __launch_bounds__(256) void knn_kernel(
    const float4* __restrict__ pk, int* __restrict__ knn_out)
{
    const int b = blockIdx.x >> 8;
    const int q0 = (blockIdx.x & 255) << 4;
    const int tid = threadIdx.x;
    const int ql = tid >> 4, t = tid & 15;
    const int n = q0 + ql;
    __shared__ float sd[16][16][16];
    __shared__ int   si[16][16][16];

    const float4* base = pk + (size_t)b * N2;
    float4 qp = base[n];
    const float ax = qp.x, ay = qp.y, az = qp.z, sa = qp.w;

    float d[16]; int id[16];
#pragma unroll
    for (int s = 0; s < 16; ++s) { d[s] = FLT_MAX; id[s] = 0; }
    const int jbase = t << 8;
    for (int jj = 0; jj < 256; ++jj) {
        int j = jbase + jj;
        float4 cp = base[j];
        float dist = dist_ref(sa, cp.w, ax, ay, az, cp.x, cp.y, cp.z);
        if (dist < d[15]) {
#pragma unroll
            for (int s = 15; s >= 0; --s) {
                bool shift = (s > 0) && (dist < d[s - 1]);
                bool place = (dist < d[s]) && !shift;
                float nd = shift ? d[s - 1] : (place ? dist : d[s]);
                int   ni = shift ? id[s - 1] : (place ? j : id[s]);
                d[s] = nd; id[s] = ni;
            }
        }
    }
#pragma unroll
    for (int s = 0; s < 16; ++s) { sd[ql][t][s] = d[s]; si[ql][t][s] = id[s]; }
    __syncthreads();
    if (t == 0) {
        int ptr[16];
#pragma unroll
        for (int u = 0; u < 16; ++u) ptr[u] = 0;
        size_t ob = ((size_t)b * N2 + n) * 16;
        for (int o = 0; o < 16; ++o) {
            int bu = 0;
            float bd = (ptr[0] < 16) ? sd[ql][0][ptr[0]] : FLT_MAX;
            for (int u = 1; u < 16; ++u) {
                float hu = (ptr[u] < 16) ? sd[ql][u][ptr[u]] : FLT_MAX;
                if (hu < bd) { bd = hu; bu = u; }
            }
            knn_out[ob + o] = si[ql][bu][ptr[bu]];
            ++ptr[bu];
        }
    }
}

// ---------------------------------------------------------------------------
// MFMA attention, 2 points per block (unchanged — bit-identical)
// ---------------------------------------------------------------------------
__global__ __launch_bounds__(256) void attn_mfma2(
    const float* __restrict__ xyz2, const float* __restrict__ qg,
    const float* __restrict__ kg, const float* __restrict__ vg,
    const int* __restrict__ knn,
    const float* __restrict__ d1w, const float* __restrict__ d1b,
    const float* __restrict__ d2b, const float* __restrict__ g1b,
    const float* __restrict__ g2b,
    const unsigned short* __restrict__ Bd2,
    const unsigned short* __restrict__ Bg1,
    const unsigned short* __restrict__ Bg2,
    float* __restrict__ res)
{
    const int bn0 = blockIdx.x * PPB;
    const int b = bn0 >> 12;
    const int c = threadIdx.x;
    const int l = c & 63, wv_ = c >> 6;
    const int lr = l & 15, lg = l >> 4;

    __shared__ __align__(16) unsigned short phb[PPB * 16][264];
    __shared__ __align__(16) unsigned short posb[PPB * 16][264];
    __shared__ int   knn_s[PPB][16];
    __shared__ float relx[PPB][16], rely[PPB][16], relz[PPB][16];

    if (c < PPB * 16) {
        int p = c >> 4, kk = c & 15;
        int idx = knn[(size_t)(bn0 + p) * 16 + kk];
        knn_s[p][kk] = idx;
        const float* pq = xyz2 + (size_t)(bn0 + p) * 3;
        const float* pk = xyz2 + ((size_t)b * N2 + idx) * 3;
        relx[p][kk] = bf16r(pq[0] - pk[0]);
        rely[p][kk] = bf16r(pq[1] - pk[1]);
        relz[p][kk] = bf16r(pq[2] - pk[2]);
    }
    __syncthreads();

    const size_t basebc = (size_t)b * N2 * 256;
    float kf[PPB][16], qv[PPB];
#pragma unroll
    for (int p = 0; p < PPB; ++p) {
        qv[p] = qg[(size_t)(bn0 + p) * 256 + c];
#pragma unroll
        for (int kk = 0; kk < 16; ++kk)
            kf[p][kk] = kg[basebc + (size_t)knn_s[p][kk] * 256 + c];
    }

    {
        float w0 = bf16r(d1w[c]), w1 = bf16r(d1w[256 + c]), w2 = bf16r(d1w[512 + c]);
        float bb = d1b[c];
#pragma unroll
        for (int p = 0; p < PPB; ++p)
#pragma unroll
            for (int kk = 0; kk < 16; ++kk) {
                float v = fmaf(relx[p][kk], w0, fmaf(rely[p][kk], w1, fmaf(relz[p][kk], w2, bb)));
                phb[p * 16 + kk][c] = f2bu(fmaxf(v, 0.f));
            }
    }
    __syncthreads();

    f32x4 acc[PPB][4];
#pragma unroll
    for (int p = 0; p < PPB; ++p)
#pragma unroll
        for (int t = 0; t < 4; ++t) acc[p][t] = (f32x4){0.f, 0.f, 0.f, 0.f};
    for (int kb = 0; kb < 8; ++kb) {
        bf16x8 bfr[4];
#pragma unroll
        for (int t = 0; t < 4; ++t)
            bfr[t] = *(const bf16x8*)&Bd2[((size_t)(kb * 16 + wv_ * 4 + t) * 64 + l) * 8];
#pragma unroll
        for (int p = 0; p < PPB; ++p) {
            bf16x8 af = *(const bf16x8*)&phb[p * 16 + lr][kb * 32 + lg * 8];
#pragma unroll
            for (int t = 0; t < 4; ++t)
                acc[p][t] = __builtin_amdgcn_mfma_f32_16x16x32_bf16(af, bfr[t], acc[p][t], 0, 0, 0);
        }
    }
#pragma unroll
    for (int p = 0; p < PPB; ++p)
#pragma unroll
        for (int t = 0; t < 4; ++t) {
            int col = (wv_ * 4 + t) * 16 + lr;
            float bb = d2b[col];
#pragma unroll
            for (int r = 0; r < 4; ++r)
                posb[p * 16 + lg * 4 + r][col] = f2bu(acc[p][t][r] + bb);
        }
    __syncthreads();

    float posr[PPB][16];
#pragma unroll
    for (int p = 0; p < PPB; ++p)
#pragma unroll
        for (int kk = 0; kk < 16; ++kk) posr[p][kk] = bu2f(posb[p * 16 + kk][c]);
#pragma unroll
    for (int p = 0; p < PPB; ++p)
#pragma unroll
        for (int kk = 0; kk < 16; ++kk)
            phb[p * 16 + kk][c] = f2bu(bf16r(qv[p] - kf[p][kk]) + posr[p][kk]);
    __syncthreads();

#pragma unroll
    for (int p = 0; p < PPB; ++p)
#pragma unroll
        for (int t = 0; t < 4; ++t) acc[p][t] = (f32x4){0.f, 0.f, 0.f, 0.f};
    for (int kb = 0; kb < 8; ++kb) {
        bf16x8 bfr[4];
#pragma unroll
        for (int t = 0; t < 4; ++t)
            bfr[t] = *(const bf16x8*)&Bg1[((size_t)(kb * 16 + wv_ * 4 + t) * 64 + l) * 8];
#pragma unroll
        for (int p = 0; p < PPB; ++p) {
            bf16x8 af = *(const bf16x8*)&phb[p * 16 + lr][kb * 32 + lg * 8];
#pragma unroll
            for (int t = 0; t < 4; ++t)
                acc[p][t] = __builtin_amdgcn_mfma_f32_16x16x32_bf16(af, bfr[t], acc[p][t], 0, 0, 0);
        }
    }
    __syncthreads();
#pragma unroll
    for (int p = 0; p < PPB; ++p)
#pragma unroll
        for (int t = 0; t < 4; ++t) {
            int col = (wv_ * 4 + t) * 16 + lr;
            float bb = g1b[col];
#pragma unroll
            for (int r = 0; r < 4; ++r)
                phb[p * 16 + lg * 4 + r][col] = f2bu(fmaxf(acc[p][t][r] + bb, 0.f));
        }
    __syncthreads();

#pragma unroll
    for (int p = 0; p < PPB; ++p)
#pragma unroll
        for (int t = 0; t < 4; ++t) acc[p][t] = (f32x4){0.f, 0.f, 0.f, 0.f};
    for (int kb = 0; kb < 8; ++kb) {
        bf16x8 bfr[4];
#pragma unroll
        for (int t = 0; t < 4; ++t)
            bfr[t] = *(const bf16x8*)&Bg2[((size_t)(kb * 16 + wv_ * 4 + t) * 64 + l) * 8];
#pragma unroll
        for (int p = 0; p < PPB; ++p) {
            bf16x8 af = *(const bf16x8*)&phb[p * 16 + lr][kb * 32 + lg * 8];
#pragma unroll
            for (int t = 0; t < 4; ++t)
                acc[p][t] = __builtin_amdgcn_mfma_f32_16x16x32_bf16(af, bfr[t], acc[p][t], 0, 0, 0);
        }
    }
#pragma unroll
    for (int p = 0; p < PPB; ++p)
#pragma unroll
        for (int t = 0; t < 4; ++t) {
            int col = (wv_ * 4 + t) * 16 + lr;
            float bb = g2b[col];
#pragma unroll
            for (int r = 0; r < 4; ++r)
                posb[p * 16 + lg * 4 + r][col] = f2bu(acc[p][t][r] + bb);
        }
    __syncthreads();

#pragma unroll
    for (int p = 0; p < PPB; ++p) {
        float av[16];
#pragma unroll
        for (int kk = 0; kk < 16; ++kk) av[kk] = bu2f(posb[p * 16 + kk][c]) * 0.0625f;
        float m = av[0];
#pragma unroll
        for (int kk = 1; kk < 16; ++kk) m = fmaxf(m, av[kk]);
        float e[16];
        float s = 0.f;
#pragma unroll
        for (int kk = 0; kk < 16; ++kk) {
            e[kk] = bf16r(expf(av[kk] - m));
            s += e[kk];
        }
#pragma unroll
        for (int kk = 0; kk < 16; ++kk) e[kk] = bf16r(e[kk] / s);
        float rr = 0.f;
#pragma unroll
        for (int kk = 0; kk < 16; ++kk) {
            float vfv = vg[basebc + (size_t)knn_s[p][kk] * 256 + c];
            float vp = bf16r(vfv + posr[p][kk]);
            rr = fmaf(e[kk], vp, rr);
        }
        res[(size_t)(bn0 + p) * 256 + c] = bf16r(rr);
    }
}

// ---------------------------------------------------------------------------
extern "C" void kernel_launch(void* const* d_in, const int* in_sizes, int n_in,
                              void* d_out, int out_size, void* d_ws, size_t ws_size,
                              hipStream_t stream)
{
    const float* xyz1     = (const float*)d_in[0];
    const float* points1  = (const float*)d_in[1];
    const float* xyz2     = (const float*)d_in[2];
    const float* points2  = (const float*)d_in[3];
    const float* up_w1    = (const float*)d_in[4];
    const float* up_b1    = (const float*)d_in[5];
    const float* up_w2    = (const float*)d_in[6];
    const float* up_b2    = (const float*)d_in[7];
    const float* fc1_w    = (const float*)d_in[8];
    const float* fc1_b    = (const float*)d_in[9];
    const float* fc2_w    = (const float*)d_in[10];
    const float* fc2_b    = (const float*)d_in[11];
    const float* delta_w1 = (const float*)d_in[12];
    const float* delta_b1 = (const float*)d_in[13];
    const float* delta_w2 = (const float*)d_in[14];
    const float* delta_b2 = (const float*)d_in[15];
    const float* gamma_w1 = (const float*)d_in[16];
    const float* gamma_b1 = (const float*)d_in[17];
    const float* gamma_w2 = (const float*)d_in[18];
    const float* gamma_b2 = (const float*)d_in[19];
    const float* wq       = (const float*)d_in[20];
    const float* wk       = (const float*)d_in[21];
    const float* wv       = (const float*)d_in[22];

    float* ws = (float*)d_ws;
    float* f1    = ws;
    float* feats = f1 + (size_t)BB * N1 * 256;
    float* x     = feats + (size_t)BB * N2 * 256;
    float* qb    = x + (size_t)BB * N2 * 256;
    float* kb    = qb + (size_t)BB * N2 * 256;
    float* vb    = kb + (size_t)BB * N2 * 256;
    int*   knn   = (int*)(vb + (size_t)BB * N2 * 256);
    unsigned short* Bd2  = (unsigned short*)(knn + (size_t)BB * N2 * 16);
    unsigned short* Bg1  = Bd2 + 65536;
    unsigned short* Bg2  = Bg1 + 65536;
    unsigned short* Bup1 = Bg2 + 65536;
    unsigned short* Bup2 = Bup1 + 131072;
    unsigned short* Bfc1 = Bup2 + 65536;
    unsigned short* Bfc2 = Bfc1 + 65536;
    unsigned short* Bq   = Bfc2 + 65536;
    unsigned short* Bk   = Bq + 65536;
    unsigned short* Bv   = Bk + 65536;
    float4* pkbuf = (float4*)(Bv + 65536);
    float* resb = x;   // x dead after q/k/v

    float* out = (float*)d_out;
    hipMemcpyAsync(out, xyz2, (size_t)BB * N2 * 3 * sizeof(float),
                   hipMemcpyDeviceToDevice, stream);

    const float BN = (float)(1.0 / sqrt(1.0 + 1e-5));

    SwzArgs sa;
    sa.W[0] = up_w1;    sa.B[0] = Bup1; sa.K[0] = CIN;
    sa.W[1] = up_w2;    sa.B[1] = Bup2; sa.K[1] = CC;
    sa.W[2] = fc1_w;    sa.B[2] = Bfc1; sa.K[2] = CC;
    sa.W[3] = fc2_w;    sa.B[3] = Bfc2; sa.K[3] = CC;
    sa.W[4] = wq;       sa.B[4] = Bq;   sa.K[4] = CC;
    sa.W[5] = wk;       sa.B[5] = Bk;   sa.K[5] = CC;
    sa.W[6] = wv;       sa.B[6] = Bv;   sa.K[6] = CC;
    sa.W[7] = delta_w2; sa.B[7] = Bd2;  sa.K[7] = CC;
    sa.W[8] = gamma_w1; sa.B[8] = Bg1;  sa.K[8] = CC;
    sa.W[9] = gamma_w2; sa.B[9] = Bg2;  sa.K[9] = CC;
    swizzle_all<<<dim3(64, 10), 256, 0, stream>>>(sa);

    pack_kernel<<<BB * N2 / 256, 256, 0, stream>>>(xyz2, pkbuf);

    // f2: NT=4 -> 1024 blocks
    gemm_mfma<CC, 4, true, true, false><<<BB * N2 / 64 * 4, 256, 0, stream>>>(
        points2, Bup2, up_b2, nullptr, BN, feats);
    // f1: NT=2 -> 512 blocks
    gemm_mfma<CIN, 2, true, true, false><<<BB * N1 / 64 * 8, 256, 0, stream>>>(
        points1, Bup1, up_b1, nullptr, BN, f1);
    nn3_interp_kernel<<<BB * 64, 256, 0, stream>>>(xyz1, xyz2, f1, feats);
    // x: NT=4 -> 1024 blocks
    gemm_mfma<CC, 4, false, false, false><<<BB * N2 / 64 * 4, 256, 0, stream>>>(
        feats, Bfc1, fc1_b, nullptr, 1.f, x);
    // qkv: NT=4 -> 1024 blocks
    qkv_mfma<<<BB * N2 / 64 * 4, 256, 0, stream>>>(x, Bq, Bk, Bv, qb, kb, vb);
    knn_kernel<<<BB * 256, 256, 0, stream>>>(pkbuf, knn);
    attn_mfma2<<<BB * N2 / PPB, 256, 0, stream>>>(xyz2, qb, kb, vb, knn,
                                                  delta_w1, delta_b1, delta_b2, gamma_b1, gamma_b2,
                                                  Bd2, Bg1, Bg2, resb);
    // out1: NT=4 -> 1024 blocks
    gemm_mfma<CC, 4, false, false, true><<<BB * N2 / 64 * 4, 256, 0, stream>>>(
        resb, Bfc2, fc2_b, feats, 1.f, out + (size_t)BB * N2 * 3);
}